// Round 2
// baseline (1991.125 us; speedup 1.0000x reference)
//
#include <hip/hip_runtime.h>
#include <hip/hip_bf16.h>

#define B_   4
#define L_   2048
#define DM_  1024
#define DIN_ 2048
#define NS_  16
#define R_   64
#define KC_  4
#define H_   1024
#define BL_  (B_ * L_)   // 8192 tokens

typedef __attribute__((ext_vector_type(4))) float f32x4;
typedef __attribute__((ext_vector_type(8))) short bf16x8;

__device__ __forceinline__ float b2f(unsigned short u) {
    union { unsigned int i; float f; } v; v.i = ((unsigned int)u) << 16; return v.f;
}
__device__ __forceinline__ unsigned short f2b(float f) {
    union { float f; unsigned int i; } v; v.f = f;
    unsigned int r = v.i + 0x7fffu + ((v.i >> 16) & 1u);
    return (unsigned short)(r >> 16);
}
__device__ __forceinline__ float sigmoidf_(float x) { return 1.f / (1.f + __expf(-x)); }
__device__ __forceinline__ float softplusf_(float x) { return (x > 20.f) ? x : log1pf(__expf(x)); }

__device__ __forceinline__ void gload16(const unsigned short* g, unsigned short* l) {
    __builtin_amdgcn_global_load_lds(
        (__attribute__((address_space(1))) void*)(g),
        (__attribute__((address_space(3))) void*)(l), 16, 0, 0);
}

// ---------------- small elementwise kernels ----------------
__global__ void k_cvt(const float* __restrict__ in, unsigned short* __restrict__ out, int n) {
    int i = blockIdx.x * blockDim.x + threadIdx.x;
    if (i < n) out[i] = f2b(in[i]);
}
__global__ void k_fill0(unsigned short* __restrict__ out, int n) {
    int i = blockIdx.x * blockDim.x + threadIdx.x;
    if (i < n) out[i] = 0;
}

// res = a + b (fp32 out), hn = bf16(rmsnorm(res) * w)
__global__ __launch_bounds__(256)
void k_add_rmsnorm(const float* __restrict__ a, const float* __restrict__ b,
                   const float* __restrict__ w,
                   float* __restrict__ resOut, unsigned short* __restrict__ hnOut) {
    int row = blockIdx.x, tid = threadIdx.x;
    const float4* ap = (const float4*)(a + (size_t)row * DM_);
    const float4* bp = (const float4*)(b + (size_t)row * DM_);
    float4 va = ap[tid], vb = bp[tid];
    float4 s = make_float4(va.x + vb.x, va.y + vb.y, va.z + vb.z, va.w + vb.w);
    ((float4*)(resOut + (size_t)row * DM_))[tid] = s;
    float ss = s.x * s.x + s.y * s.y + s.z * s.z + s.w * s.w;
    #pragma unroll
    for (int m = 32; m >= 1; m >>= 1) ss += __shfl_xor(ss, m);
    __shared__ float red[4];
    if ((tid & 63) == 0) red[tid >> 6] = ss;
    __syncthreads();
    float tot = red[0] + red[1] + red[2] + red[3];
    float sc = rsqrtf(tot / (float)DM_ + 1e-5f);
    float4 vw = ((const float4*)w)[tid];
    unsigned short* hp = hnOut + (size_t)row * DM_ + tid * 4;
    *(ushort4*)hp = make_ushort4(f2b(s.x * sc * vw.x), f2b(s.y * sc * vw.y),
                                 f2b(s.z * sc * vw.z), f2b(s.w * sc * vw.w));
}

// res2 = rmsnorm(mix + res) * w (fp32 out), mixB = bf16(mix)
__global__ __launch_bounds__(256)
void k_add_rmsnorm2(const float* __restrict__ mix, const float* __restrict__ res,
                    const float* __restrict__ w,
                    float* __restrict__ res2Out, unsigned short* __restrict__ mixB) {
    int row = blockIdx.x, tid = threadIdx.x;
    const float4* mp = (const float4*)(mix + (size_t)row * DM_);
    const float4* rp = (const float4*)(res + (size_t)row * DM_);
    float4 vm = mp[tid], vr = rp[tid];
    float4 s = make_float4(vm.x + vr.x, vm.y + vr.y, vm.z + vr.z, vm.w + vr.w);
    unsigned short* mb = mixB + (size_t)row * DM_ + tid * 4;
    *(ushort4*)mb = make_ushort4(f2b(vm.x), f2b(vm.y), f2b(vm.z), f2b(vm.w));
    float ss = s.x * s.x + s.y * s.y + s.z * s.z + s.w * s.w;
    #pragma unroll
    for (int m = 32; m >= 1; m >>= 1) ss += __shfl_xor(ss, m);
    __shared__ float red[4];
    if ((tid & 63) == 0) red[tid >> 6] = ss;
    __syncthreads();
    float tot = red[0] + red[1] + red[2] + red[3];
    float sc = rsqrtf(tot / (float)DM_ + 1e-5f);
    float4 vw = ((const float4*)w)[tid];
    float4 o = make_float4(s.x * sc * vw.x, s.y * sc * vw.y, s.z * sc * vw.z, s.w * sc * vw.w);
    ((float4*)(res2Out + (size_t)row * DM_))[tid] = o;
}

// depthwise causal conv K=4 + bias + silu; x part of xz (cols [0,DIN))
__global__ void k_conv_silu(const unsigned short* __restrict__ xz,
                            const float* __restrict__ cw, const float* __restrict__ cb,
                            unsigned short* __restrict__ xc) {
    int i = blockIdx.x * blockDim.x + threadIdx.x;
    if (i >= BL_ * DIN_) return;
    int d = i % DIN_;
    int t = (i / DIN_) % L_;
    int b = i / (DIN_ * L_);
    const unsigned short* xrow = xz + (size_t)b * L_ * (2 * DIN_) + d;
    float acc = cb[d];
    #pragma unroll
    for (int k = 0; k < KC_; k++) {
        int tt = t - (KC_ - 1) + k;
        if (tt >= 0) acc += b2f(xrow[(size_t)tt * (2 * DIN_)]) * cw[d * KC_ + k];
    }
    xc[i] = f2b(acc * sigmoidf_(acc));
}

// g = y * silu(gate) from fc = [y | gate]
__global__ void k_gate(const unsigned short* __restrict__ fc, unsigned short* __restrict__ g) {
    int i = blockIdx.x * blockDim.x + threadIdx.x;
    if (i >= BL_ * H_) return;
    int h = i % H_;
    int row = i / H_;
    float y = b2f(fc[(size_t)row * (2 * H_) + h]);
    float gt = b2f(fc[(size_t)row * (2 * H_) + H_ + h]);
    g[i] = f2b(y * gt * sigmoidf_(gt));
}

// ---------------- selective scan ----------------
// 16 lanes per channel (lane = state n), 16 channels per block, 512 blocks.
// dty: bf16 [B][L][DIN]; holds dt on entry, y on exit (in-place, read-before-write
// per element within the owning wave; store data depends on the loaded dt).
__global__ __launch_bounds__(256)
void k_scan(unsigned short* __restrict__ dty, const unsigned short* __restrict__ xc,
            const unsigned short* __restrict__ dbl, const float* __restrict__ A_log,
            const float* __restrict__ Dp, const unsigned short* __restrict__ xz) {
    int tid = threadIdx.x;
    int n = tid & 15;
    int grp = tid >> 4;
    int blocksPerB = DIN_ / 16;  // 128
    int b = blockIdx.x / blocksPerB;
    int d = (blockIdx.x % blocksPerB) * 16 + grp;

    float a = -expf(A_log[d * NS_ + n]);
    float Dd = Dp[d];
    unsigned short* dp = dty + (size_t)b * L_ * DIN_ + d;
    const unsigned short* xp = xc + (size_t)b * L_ * DIN_ + d;
    const unsigned short* zp = xz + (size_t)b * L_ * (2 * DIN_) + DIN_ + d;
    const unsigned short* blp = dbl + (size_t)b * L_ * 96;

    float h = 0.f;
    for (int t = 0; t < L_; t++) {
        float dtv = b2f(dp[(size_t)t * DIN_]);
        float xv = b2f(xp[(size_t)t * DIN_]);
        float Bv = b2f(blp[t * 96 + 64 + n]);
        float Cv = b2f(blp[t * 96 + 80 + n]);
        h = __expf(dtv * a) * h + (dtv * xv) * Bv;
        float p = h * Cv;
        p += __shfl_xor(p, 8);
        p += __shfl_xor(p, 4);
        p += __shfl_xor(p, 2);
        p += __shfl_xor(p, 1);
        if (n == 0) {
            float y = p + xv * Dd;
            float zv = b2f(zp[(size_t)t * (2 * DIN_)]);
            dp[(size_t)t * DIN_] = f2b(y * zv * sigmoidf_(zv));
        }
    }
}

// ---------------- GEMM: C[M,N] = A[M,K] @ W[N,K]^T, bf16 in, fp32 acc ----------------
// EPI: 0 = fp32 store, 1 = bf16 store, 2 = bias + softplus + bf16 store
template <int EPI>
__global__ __launch_bounds__(256)
void k_gemm(const unsigned short* __restrict__ A, int lda,
            const unsigned short* __restrict__ Bw, int ldb,
            void* __restrict__ outp, int ldc, const float* __restrict__ bias,
            int M, int N, int Kd, int Nstore) {
    __shared__ unsigned short As[128 * 32];
    __shared__ unsigned short Bs[128 * 32];
    const int tid = threadIdx.x;
    const int lane = tid & 63;
    const int w = tid >> 6;
    const int wr = w >> 1, wc = w & 1;
    const int bm = blockIdx.y * 128, bn = blockIdx.x * 128;

    const int e0 = tid * 8;               // element offset of this thread's 16B chunk
    const int r0 = e0 >> 5;               // row (0..63)
    const int c0 = e0 & 31;               // k-col
    const int r1 = r0 + 64;

    f32x4 acc[4][4];
    #pragma unroll
    for (int i = 0; i < 4; i++)
        #pragma unroll
        for (int j = 0; j < 4; j++) acc[i][j] = (f32x4){0.f, 0.f, 0.f, 0.f};

    const int fr = lane & 15, ko = (lane >> 4) * 8;

    for (int k0 = 0; k0 < Kd; k0 += 32) {
        gload16(A  + (size_t)(bm + r0) * lda + k0 + c0, &As[e0]);
        gload16(A  + (size_t)(bm + r1) * lda + k0 + c0, &As[e0 + 2048]);
        gload16(Bw + (size_t)(bn + r0) * ldb + k0 + c0, &Bs[e0]);
        gload16(Bw + (size_t)(bn + r1) * ldb + k0 + c0, &Bs[e0 + 2048]);
        __syncthreads();
        bf16x8 af[4], bv[4];
        #pragma unroll
        for (int i = 0; i < 4; i++)
            af[i] = *(const bf16x8*)&As[(wr * 64 + i * 16 + fr) * 32 + ko];
        #pragma unroll
        for (int j = 0; j < 4; j++)
            bv[j] = *(const bf16x8*)&Bs[(wc * 64 + j * 16 + fr) * 32 + ko];
        #pragma unroll
        for (int i = 0; i < 4; i++)
            #pragma unroll
            for (int j = 0; j < 4; j++)
                acc[i][j] = __builtin_amdgcn_mfma_f32_16x16x32_bf16(af[i], bv[j], acc[i][j], 0, 0, 0);
        __syncthreads();
    }

    const int rr = (lane >> 4) * 4;
    const int cc = lane & 15;
    #pragma unroll
    for (int i = 0; i < 4; i++) {
        #pragma unroll
        for (int j = 0; j < 4; j++) {
            int col = bn + wc * 64 + j * 16 + cc;
            if (col >= Nstore) continue;
            #pragma unroll
            for (int q = 0; q < 4; q++) {
                int row = bm + wr * 64 + i * 16 + rr + q;
                float v = acc[i][j][q];
                if constexpr (EPI == 2) { v += bias[col]; v = softplusf_(v); }
                if constexpr (EPI == 0)
                    ((float*)outp)[(size_t)row * ldc + col] = v;
                else
                    ((unsigned short*)outp)[(size_t)row * ldc + col] = f2b(v);
            }
        }
    }
}

// ---------------- host ----------------
extern "C" void kernel_launch(void* const* d_in, const int* in_sizes, int n_in,
                              void* d_out, int out_size, void* d_ws, size_t ws_size,
                              hipStream_t stream) {
    const float* hs        = (const float*)d_in[0];
    const float* resi      = (const float*)d_in[1];
    const float* norm_w    = (const float*)d_in[2];
    const float* in_proj_w = (const float*)d_in[3];
    const float* conv_w    = (const float*)d_in[4];
    const float* conv_b    = (const float*)d_in[5];
    const float* x_proj_w  = (const float*)d_in[6];
    const float* dt_proj_w = (const float*)d_in[7];
    const float* dt_proj_b = (const float*)d_in[8];
    const float* A_log     = (const float*)d_in[9];
    const float* Dp        = (const float*)d_in[10];
    const float* out_proj_w= (const float*)d_in[11];
    const float* norm2_w   = (const float*)d_in[12];
    const float* fc1_w     = (const float*)d_in[13];
    const float* fc2_w     = (const float*)d_in[14];

    char* ws = (char*)d_ws;
    size_t off = 0;
    auto alloc = [&](size_t bytes) {
        void* p = ws + off;
        off = (off + bytes + 255) & ~(size_t)255;
        return p;
    };

    // --- workspace overlay (total ~116 MB) ---
    // S_xz (64MB): xz [k2..k6]; then mixB/fcB/gB [k8..k11]
    unsigned short* xzB  = (unsigned short*)alloc((size_t)BL_ * 2 * DIN_ * 2);
    unsigned short* fcB  = xzB;                              // 32MB, [k9..k10]
    unsigned short* gB   = xzB + (size_t)BL_ * 2 * H_;       // 16MB, [k10..k11]
    unsigned short* mixB = gB  + (size_t)BL_ * H_;           // 16MB, [k8..k9]
    // S_xc (32MB): hn [k1..k2]; xconv [k3..k6]; mixF fp32 [k7..k8]
    void* S_xc = alloc((size_t)BL_ * DIN_ * 2);
    unsigned short* hnB    = (unsigned short*)S_xc;
    unsigned short* xconvB = (unsigned short*)S_xc;
    float*          mixF   = (float*)S_xc;
    // dbl (1.5MB): [k4..k6]
    unsigned short* dblB = (unsigned short*)alloc((size_t)BL_ * 96 * 2);
    // bf16 weights (~19MB), live all
    unsigned short* inprojB  = (unsigned short*)alloc((size_t)2 * DIN_ * DM_ * 2);
    unsigned short* xprojB   = (unsigned short*)alloc((size_t)128 * DIN_ * 2);  // padded 96->128
    unsigned short* dtprojB  = (unsigned short*)alloc((size_t)DIN_ * R_ * 2);
    unsigned short* outprojB = (unsigned short*)alloc((size_t)DM_ * DIN_ * 2);
    unsigned short* fc1B     = (unsigned short*)alloc((size_t)2 * H_ * DM_ * 2);
    unsigned short* fc2B     = (unsigned short*)alloc((size_t)DM_ * H_ * 2);

    // --- d_out doubles as scratch ---
    float* outMain = (float*)d_out;                          // final: out  [k11]
    float* outRes2 = (float*)d_out + (size_t)BL_ * DM_;      // final: res2 [k8]
    float*          resF = outMain;                // fp32 res, [k1..k8] (k11 overwrites)
    unsigned short* dtyB = (unsigned short*)outRes2; // bf16 dt[k5..k6] -> y[k6..k7] (k8 overwrites)

    // weight converts
    {
        int n;
        n = 2 * DIN_ * DM_; k_cvt<<<(n + 255) / 256, 256, 0, stream>>>(in_proj_w, inprojB, n);
        n = 96 * DIN_;      k_cvt<<<(n + 255) / 256, 256, 0, stream>>>(x_proj_w, xprojB, n);
        n = 32 * DIN_;      k_fill0<<<(n + 255) / 256, 256, 0, stream>>>(xprojB + 96 * DIN_, n);
        n = DIN_ * R_;      k_cvt<<<(n + 255) / 256, 256, 0, stream>>>(dt_proj_w, dtprojB, n);
        n = DM_ * DIN_;     k_cvt<<<(n + 255) / 256, 256, 0, stream>>>(out_proj_w, outprojB, n);
        n = 2 * H_ * DM_;   k_cvt<<<(n + 255) / 256, 256, 0, stream>>>(fc1_w, fc1B, n);
        n = DM_ * H_;       k_cvt<<<(n + 255) / 256, 256, 0, stream>>>(fc2_w, fc2B, n);
    }

    // 1) res = hs + residual ; hn = rmsnorm(res)
    k_add_rmsnorm<<<BL_, 256, 0, stream>>>(hs, resi, norm_w, resF, hnB);

    // 2) xz = hn @ in_proj^T   (M=8192, N=4096, K=1024)
    k_gemm<1><<<dim3(2 * DIN_ / 128, BL_ / 128), 256, 0, stream>>>(
        hnB, DM_, inprojB, DM_, (void*)xzB, 2 * DIN_, nullptr, BL_, 2 * DIN_, DM_, 2 * DIN_);

    // 3) depthwise conv + silu   (hn dead; xconv takes S_xc)
    k_conv_silu<<<(BL_ * DIN_ + 255) / 256, 256, 0, stream>>>(xzB, conv_w, conv_b, xconvB);

    // 4) dbl = x @ x_proj^T    (M=8192, N=128(pad), K=2048, store 96)
    k_gemm<1><<<dim3(1, BL_ / 128), 256, 0, stream>>>(
        xconvB, DIN_, xprojB, DIN_, (void*)dblB, 96, nullptr, BL_, 128, DIN_, 96);

    // 5) dt = softplus(dt_low @ dt_proj^T + b) -> bf16  (M=8192, N=2048, K=64)
    k_gemm<2><<<dim3(DIN_ / 128, BL_ / 128), 256, 0, stream>>>(
        dblB, 96, dtprojB, R_, (void*)dtyB, DIN_, dt_proj_b, BL_, DIN_, R_, DIN_);

    // 6) selective scan + D skip + z gate; y overwrites dt in place
    k_scan<<<B_ * (DIN_ / 16), 256, 0, stream>>>(dtyB, xconvB, dblB, A_log, Dp, xzB);

    // 7) mix = y @ out_proj^T  (M=8192, N=1024, K=2048)  (xconv dead; mixF takes S_xc)
    k_gemm<0><<<dim3(DM_ / 128, BL_ / 128), 256, 0, stream>>>(
        dtyB, DIN_, outprojB, DIN_, (void*)mixF, DM_, nullptr, BL_, DM_, DIN_, DM_);

    // 8) res2 = rmsnorm(mix + res) -> d_out[1] (overwrites dty scratch); mixB = bf16(mix)
    k_add_rmsnorm2<<<BL_, 256, 0, stream>>>(mixF, resF, norm2_w, outRes2, mixB);

    // 9) fc = mix @ fc1^T      (M=8192, N=2048, K=1024)  (xz dead; fc takes S_xz)
    k_gemm<1><<<dim3(2 * H_ / 128, BL_ / 128), 256, 0, stream>>>(
        mixB, DM_, fc1B, DM_, (void*)fcB, 2 * H_, nullptr, BL_, 2 * H_, DM_, 2 * H_);

    // 10) g = y * silu(gate)
    k_gate<<<(BL_ * H_ + 255) / 256, 256, 0, stream>>>(fcB, gB);

    // 11) out = g @ fc2^T      (M=8192, N=1024, K=1024) -> d_out[0] (overwrites res)
    k_gemm<0><<<dim3(DM_ / 128, BL_ / 128), 256, 0, stream>>>(
        gB, H_, fc2B, H_, (void*)outMain, DM_, nullptr, BL_, DM_, H_, DM_);
}

// Round 3
// 670.028 us; speedup vs baseline: 2.9717x; 2.9717x over previous
//
#include <hip/hip_runtime.h>
#include <hip/hip_bf16.h>

#define B_   4
#define L_   2048
#define DM_  1024
#define DIN_ 2048
#define NS_  16
#define R_   64
#define KC_  4
#define H_   1024
#define BL_  (B_ * L_)   // 8192 tokens
#define CCH  16          // scan chunks
#define CHL  (L_ / CCH)  // 128 steps per chunk

typedef __attribute__((ext_vector_type(4))) float f32x4;
typedef __attribute__((ext_vector_type(8))) short bf16x8;
typedef __attribute__((ext_vector_type(8))) unsigned short u16x8;

__device__ __forceinline__ float b2f(unsigned short u) {
    union { unsigned int i; float f; } v; v.i = ((unsigned int)u) << 16; return v.f;
}
__device__ __forceinline__ unsigned short f2b(float f) {
    union { float f; unsigned int i; } v; v.f = f;
    unsigned int r = v.i + 0x7fffu + ((v.i >> 16) & 1u);
    return (unsigned short)(r >> 16);
}
__device__ __forceinline__ float sigmoidf_(float x) { return 1.f / (1.f + __expf(-x)); }
__device__ __forceinline__ float softplusf_(float x) { return (x > 20.f) ? x : log1pf(__expf(x)); }

__device__ __forceinline__ void gload16(const unsigned short* g, unsigned short* l) {
    __builtin_amdgcn_global_load_lds(
        (__attribute__((address_space(1))) void*)(g),
        (__attribute__((address_space(3))) void*)(l), 16, 0, 0);
}

// ---------------- small elementwise kernels ----------------
__global__ void k_cvt(const float* __restrict__ in, unsigned short* __restrict__ out, int n) {
    int i = blockIdx.x * blockDim.x + threadIdx.x;
    if (i < n) out[i] = f2b(in[i]);
}
__global__ void k_fill0(unsigned short* __restrict__ out, int n) {
    int i = blockIdx.x * blockDim.x + threadIdx.x;
    if (i < n) out[i] = 0;
}

// res = a + b (fp32 out), hn = bf16(rmsnorm(res) * w)
__global__ __launch_bounds__(256)
void k_add_rmsnorm(const float* __restrict__ a, const float* __restrict__ b,
                   const float* __restrict__ w,
                   float* __restrict__ resOut, unsigned short* __restrict__ hnOut) {
    int row = blockIdx.x, tid = threadIdx.x;
    const float4* ap = (const float4*)(a + (size_t)row * DM_);
    const float4* bp = (const float4*)(b + (size_t)row * DM_);
    float4 va = ap[tid], vb = bp[tid];
    float4 s = make_float4(va.x + vb.x, va.y + vb.y, va.z + vb.z, va.w + vb.w);
    ((float4*)(resOut + (size_t)row * DM_))[tid] = s;
    float ss = s.x * s.x + s.y * s.y + s.z * s.z + s.w * s.w;
    #pragma unroll
    for (int m = 32; m >= 1; m >>= 1) ss += __shfl_xor(ss, m);
    __shared__ float red[4];
    if ((tid & 63) == 0) red[tid >> 6] = ss;
    __syncthreads();
    float tot = red[0] + red[1] + red[2] + red[3];
    float sc = rsqrtf(tot / (float)DM_ + 1e-5f);
    float4 vw = ((const float4*)w)[tid];
    unsigned short* hp = hnOut + (size_t)row * DM_ + tid * 4;
    *(ushort4*)hp = make_ushort4(f2b(s.x * sc * vw.x), f2b(s.y * sc * vw.y),
                                 f2b(s.z * sc * vw.z), f2b(s.w * sc * vw.w));
}

// res2 = rmsnorm(mix + res) * w (fp32 out), mixB = bf16(mix)
__global__ __launch_bounds__(256)
void k_add_rmsnorm2(const float* __restrict__ mix, const float* __restrict__ res,
                    const float* __restrict__ w,
                    float* __restrict__ res2Out, unsigned short* __restrict__ mixB) {
    int row = blockIdx.x, tid = threadIdx.x;
    const float4* mp = (const float4*)(mix + (size_t)row * DM_);
    const float4* rp = (const float4*)(res + (size_t)row * DM_);
    float4 vm = mp[tid], vr = rp[tid];
    float4 s = make_float4(vm.x + vr.x, vm.y + vr.y, vm.z + vr.z, vm.w + vr.w);
    unsigned short* mb = mixB + (size_t)row * DM_ + tid * 4;
    *(ushort4*)mb = make_ushort4(f2b(vm.x), f2b(vm.y), f2b(vm.z), f2b(vm.w));
    float ss = s.x * s.x + s.y * s.y + s.z * s.z + s.w * s.w;
    #pragma unroll
    for (int m = 32; m >= 1; m >>= 1) ss += __shfl_xor(ss, m);
    __shared__ float red[4];
    if ((tid & 63) == 0) red[tid >> 6] = ss;
    __syncthreads();
    float tot = red[0] + red[1] + red[2] + red[3];
    float sc = rsqrtf(tot / (float)DM_ + 1e-5f);
    float4 vw = ((const float4*)w)[tid];
    float4 o = make_float4(s.x * sc * vw.x, s.y * sc * vw.y, s.z * sc * vw.z, s.w * sc * vw.w);
    ((float4*)(res2Out + (size_t)row * DM_))[tid] = o;
}

// depthwise causal conv K=4 + bias + silu; x part of xz (cols [0,DIN))
__global__ void k_conv_silu(const unsigned short* __restrict__ xz,
                            const float* __restrict__ cw, const float* __restrict__ cb,
                            unsigned short* __restrict__ xc) {
    int i = blockIdx.x * blockDim.x + threadIdx.x;
    if (i >= BL_ * DIN_) return;
    int d = i % DIN_;
    int t = (i / DIN_) % L_;
    int b = i / (DIN_ * L_);
    const unsigned short* xrow = xz + (size_t)b * L_ * (2 * DIN_) + d;
    float acc = cb[d];
    #pragma unroll
    for (int k = 0; k < KC_; k++) {
        int tt = t - (KC_ - 1) + k;
        if (tt >= 0) acc += b2f(xrow[(size_t)tt * (2 * DIN_)]) * cw[d * KC_ + k];
    }
    xc[i] = f2b(acc * sigmoidf_(acc));
}

// g = y * silu(gate) from fc = [y | gate]
__global__ void k_gate(const unsigned short* __restrict__ fc, unsigned short* __restrict__ g) {
    int i = blockIdx.x * blockDim.x + threadIdx.x;
    if (i >= BL_ * H_) return;
    int h = i % H_;
    int row = i / H_;
    float y = b2f(fc[(size_t)row * (2 * H_) + h]);
    float gt = b2f(fc[(size_t)row * (2 * H_) + H_ + h]);
    g[i] = f2b(y * gt * sigmoidf_(gt));
}

// ---------------- chunked selective scan ----------------
// Thread-per-channel: thread owns (b,d), 16 states in registers.
// Pass 1: per-chunk local scan from h=0 -> Q[b,c,d,n] (final local state), sumdt.
// Combine: per (b,d,n) sequential over 16 chunks -> chunk-initial states
//          (written into Q slot c-1; chunk 0 init = 0).
// Pass 3: re-run chunk from true init, write gated y over dt in place.

__global__ __launch_bounds__(256)
void k_scan_p1(const unsigned short* __restrict__ dty, const unsigned short* __restrict__ xc,
               const unsigned short* __restrict__ dbl, const float* __restrict__ A_log,
               float* __restrict__ Q, float* __restrict__ sumdt) {
    __shared__ float Bs[64][NS_];
    const int tid = threadIdx.x;
    const int d = (blockIdx.x & 7) * 256 + tid;
    const int b = blockIdx.x >> 3;
    const int c = blockIdx.y;
    const int t0 = c * CHL;

    float a[NS_], h[NS_];
    #pragma unroll
    for (int n = 0; n < NS_; n++) { a[n] = -__expf(A_log[d * NS_ + n]); h[n] = 0.f; }
    float sd = 0.f;

    const unsigned short* dp  = dty + (size_t)b * L_ * DIN_ + d;
    const unsigned short* xp  = xc  + (size_t)b * L_ * DIN_ + d;
    const unsigned short* blp = dbl + (size_t)b * L_ * 96;

    for (int tt = 0; tt < CHL; tt += 64) {
        __syncthreads();
        if (tid < 128) {
            int r = tid >> 1, seg = tid & 1;
            u16x8 v = *(const u16x8*)(blp + (size_t)(t0 + tt + r) * 96 + 64 + seg * 8);
            #pragma unroll
            for (int j = 0; j < 8; j++) Bs[r][seg * 8 + j] = b2f(v[j]);
        }
        __syncthreads();
        #pragma unroll 2
        for (int t = 0; t < 64; t++) {
            int tg = t0 + tt + t;
            float dtv = b2f(dp[(size_t)tg * DIN_]);
            float xv  = b2f(xp[(size_t)tg * DIN_]);
            sd += dtv;
            float bx = dtv * xv;
            #pragma unroll
            for (int n = 0; n < NS_; n++)
                h[n] = __expf(dtv * a[n]) * h[n] + bx * Bs[t][n];
        }
    }
    float* q = Q + ((size_t)(b * CCH + c) * DIN_ + d) * NS_;
    #pragma unroll
    for (int s = 0; s < 4; s++)
        ((f32x4*)q)[s] = (f32x4){h[s*4], h[s*4+1], h[s*4+2], h[s*4+3]};
    sumdt[(size_t)(b * CCH + c) * DIN_ + d] = sd;
}

__global__ __launch_bounds__(256)
void k_scan_comb(float* __restrict__ Q, const float* __restrict__ sumdt,
                 const float* __restrict__ A_log) {
    int i = blockIdx.x * 256 + threadIdx.x;   // (b,d,n), 131072 total
    int n = i & 15;
    int d = (i >> 4) & (DIN_ - 1);
    int b = i >> 15;
    float a = -__expf(A_log[d * NS_ + n]);
    float h = 0.f;
    for (int c = 0; c < CCH; c++) {
        size_t base = ((size_t)(b * CCH + c) * DIN_ + d);
        float q  = Q[base * NS_ + n];
        float sd = sumdt[base];
        if (c > 0) Q[((size_t)(b * CCH + c - 1) * DIN_ + d) * NS_ + n] = h;
        h = __expf(a * sd) * h + q;
    }
}

__global__ __launch_bounds__(256)
void k_scan_p3(unsigned short* __restrict__ dty, const unsigned short* __restrict__ xc,
               const unsigned short* __restrict__ dbl, const float* __restrict__ A_log,
               const float* __restrict__ Dp, const unsigned short* __restrict__ xz,
               const float* __restrict__ Qh) {
    __shared__ float BCs[64][32];
    const int tid = threadIdx.x;
    const int d = (blockIdx.x & 7) * 256 + tid;
    const int b = blockIdx.x >> 3;
    const int c = blockIdx.y;
    const int t0 = c * CHL;

    float a[NS_], h[NS_];
    #pragma unroll
    for (int n = 0; n < NS_; n++) a[n] = -__expf(A_log[d * NS_ + n]);
    if (c == 0) {
        #pragma unroll
        for (int n = 0; n < NS_; n++) h[n] = 0.f;
    } else {
        const float* qh = Qh + ((size_t)(b * CCH + c - 1) * DIN_ + d) * NS_;
        #pragma unroll
        for (int s = 0; s < 4; s++) {
            f32x4 v = ((const f32x4*)qh)[s];
            h[s*4] = v[0]; h[s*4+1] = v[1]; h[s*4+2] = v[2]; h[s*4+3] = v[3];
        }
    }
    float Dd = Dp[d];

    unsigned short* dp = dty + (size_t)b * L_ * DIN_ + d;
    const unsigned short* xp  = xc + (size_t)b * L_ * DIN_ + d;
    const unsigned short* zp  = xz + (size_t)b * L_ * (2 * DIN_) + DIN_ + d;
    const unsigned short* blp = dbl + (size_t)b * L_ * 96;

    for (int tt = 0; tt < CHL; tt += 64) {
        __syncthreads();
        {
            int r = tid >> 2, seg = tid & 3;
            u16x8 v = *(const u16x8*)(blp + (size_t)(t0 + tt + r) * 96 + 64 + seg * 8);
            #pragma unroll
            for (int j = 0; j < 8; j++) BCs[r][seg * 8 + j] = b2f(v[j]);
        }
        __syncthreads();
        #pragma unroll 2
        for (int t = 0; t < 64; t++) {
            int tg = t0 + tt + t;
            float dtv = b2f(dp[(size_t)tg * DIN_]);
            float xv  = b2f(xp[(size_t)tg * DIN_]);
            float bx = dtv * xv;
            float y = 0.f;
            #pragma unroll
            for (int n = 0; n < NS_; n++) {
                h[n] = __expf(dtv * a[n]) * h[n] + bx * BCs[t][n];
                y += h[n] * BCs[t][16 + n];
            }
            y += xv * Dd;
            float zv = b2f(zp[(size_t)tg * (2 * DIN_)]);
            dp[(size_t)tg * DIN_] = f2b(y * zv * sigmoidf_(zv));
        }
    }
}

// ---------------- GEMM: C[M,N] = A[M,K] @ W[N,K]^T, bf16 in, fp32 acc ----------------
// EPI: 0 = fp32 store, 1 = bf16 store, 2 = bias + softplus + bf16 store
template <int EPI>
__global__ __launch_bounds__(256)
void k_gemm(const unsigned short* __restrict__ A, int lda,
            const unsigned short* __restrict__ Bw, int ldb,
            void* __restrict__ outp, int ldc, const float* __restrict__ bias,
            int M, int N, int Kd, int Nstore) {
    __shared__ unsigned short As[128 * 32];
    __shared__ unsigned short Bs[128 * 32];
    const int tid = threadIdx.x;
    const int lane = tid & 63;
    const int w = tid >> 6;
    const int wr = w >> 1, wc = w & 1;
    const int bm = blockIdx.y * 128, bn = blockIdx.x * 128;

    const int e0 = tid * 8;               // element offset of this thread's 16B chunk
    const int r0 = e0 >> 5;               // row (0..63)
    const int c0 = e0 & 31;               // k-col
    const int r1 = r0 + 64;

    f32x4 acc[4][4];
    #pragma unroll
    for (int i = 0; i < 4; i++)
        #pragma unroll
        for (int j = 0; j < 4; j++) acc[i][j] = (f32x4){0.f, 0.f, 0.f, 0.f};

    const int fr = lane & 15, ko = (lane >> 4) * 8;

    for (int k0 = 0; k0 < Kd; k0 += 32) {
        gload16(A  + (size_t)(bm + r0) * lda + k0 + c0, &As[e0]);
        gload16(A  + (size_t)(bm + r1) * lda + k0 + c0, &As[e0 + 2048]);
        gload16(Bw + (size_t)(bn + r0) * ldb + k0 + c0, &Bs[e0]);
        gload16(Bw + (size_t)(bn + r1) * ldb + k0 + c0, &Bs[e0 + 2048]);
        __syncthreads();
        bf16x8 af[4], bv[4];
        #pragma unroll
        for (int i = 0; i < 4; i++)
            af[i] = *(const bf16x8*)&As[(wr * 64 + i * 16 + fr) * 32 + ko];
        #pragma unroll
        for (int j = 0; j < 4; j++)
            bv[j] = *(const bf16x8*)&Bs[(wc * 64 + j * 16 + fr) * 32 + ko];
        #pragma unroll
        for (int i = 0; i < 4; i++)
            #pragma unroll
            for (int j = 0; j < 4; j++)
                acc[i][j] = __builtin_amdgcn_mfma_f32_16x16x32_bf16(af[i], bv[j], acc[i][j], 0, 0, 0);
        __syncthreads();
    }

    const int rr = (lane >> 4) * 4;
    const int cc = lane & 15;
    #pragma unroll
    for (int i = 0; i < 4; i++) {
        #pragma unroll
        for (int j = 0; j < 4; j++) {
            int col = bn + wc * 64 + j * 16 + cc;
            if (col >= Nstore) continue;
            #pragma unroll
            for (int q = 0; q < 4; q++) {
                int row = bm + wr * 64 + i * 16 + rr + q;
                float v = acc[i][j][q];
                if constexpr (EPI == 2) { v += bias[col]; v = softplusf_(v); }
                if constexpr (EPI == 0)
                    ((float*)outp)[(size_t)row * ldc + col] = v;
                else
                    ((unsigned short*)outp)[(size_t)row * ldc + col] = f2b(v);
            }
        }
    }
}

// ---------------- host ----------------
extern "C" void kernel_launch(void* const* d_in, const int* in_sizes, int n_in,
                              void* d_out, int out_size, void* d_ws, size_t ws_size,
                              hipStream_t stream) {
    const float* hs        = (const float*)d_in[0];
    const float* resi      = (const float*)d_in[1];
    const float* norm_w    = (const float*)d_in[2];
    const float* in_proj_w = (const float*)d_in[3];
    const float* conv_w    = (const float*)d_in[4];
    const float* conv_b    = (const float*)d_in[5];
    const float* x_proj_w  = (const float*)d_in[6];
    const float* dt_proj_w = (const float*)d_in[7];
    const float* dt_proj_b = (const float*)d_in[8];
    const float* A_log     = (const float*)d_in[9];
    const float* Dp        = (const float*)d_in[10];
    const float* out_proj_w= (const float*)d_in[11];
    const float* norm2_w   = (const float*)d_in[12];
    const float* fc1_w     = (const float*)d_in[13];
    const float* fc2_w     = (const float*)d_in[14];

    char* ws = (char*)d_ws;
    size_t off = 0;
    auto alloc = [&](size_t bytes) {
        void* p = ws + off;
        off = (off + bytes + 255) & ~(size_t)255;
        return p;
    };

    // --- workspace overlay (total ~116 MB) ---
    // S_xz (64MB): xz [k2..k6]; then mixB/fcB/gB [k8..k11]
    unsigned short* xzB  = (unsigned short*)alloc((size_t)BL_ * 2 * DIN_ * 2);
    unsigned short* fcB  = xzB;                              // 32MB, [k9..k10]
    unsigned short* gB   = xzB + (size_t)BL_ * 2 * H_;       // 16MB, [k10..k11]
    unsigned short* mixB = gB  + (size_t)BL_ * H_;           // 16MB, [k8..k9]
    // S_xc (32MB): hn [k1..k2]; xconv [k3..k6]; mixF fp32 [k7..k8]
    void* S_xc = alloc((size_t)BL_ * DIN_ * 2);
    unsigned short* hnB    = (unsigned short*)S_xc;
    unsigned short* xconvB = (unsigned short*)S_xc;
    float*          mixF   = (float*)S_xc;
    // dbl (1.5MB): [k4..k6]
    unsigned short* dblB = (unsigned short*)alloc((size_t)BL_ * 96 * 2);
    // bf16 weights (~19MB)
    unsigned short* inprojB  = (unsigned short*)alloc((size_t)2 * DIN_ * DM_ * 2);  // dead after k2
    unsigned short* xprojB   = (unsigned short*)alloc((size_t)128 * DIN_ * 2);  // padded 96->128
    unsigned short* dtprojB  = (unsigned short*)alloc((size_t)DIN_ * R_ * 2);
    unsigned short* outprojB = (unsigned short*)alloc((size_t)DM_ * DIN_ * 2);
    unsigned short* fc1B     = (unsigned short*)alloc((size_t)2 * H_ * DM_ * 2);
    unsigned short* fc2B     = (unsigned short*)alloc((size_t)DM_ * H_ * 2);

    // scan scratch overlays inprojB (dead after k2; scan runs at k6). 8.9MB < 16MB.
    float* scanQ  = (float*)inprojB;                          // [B][CCH][DIN][16] f32
    float* scanSd = scanQ + (size_t)B_ * CCH * DIN_ * NS_;    // [B][CCH][DIN] f32

    // --- d_out doubles as scratch ---
    float* outMain = (float*)d_out;                          // final: out  [k11]
    float* outRes2 = (float*)d_out + (size_t)BL_ * DM_;      // final: res2 [k8]
    float*          resF = outMain;                // fp32 res, [k1..k8] (k11 overwrites)
    unsigned short* dtyB = (unsigned short*)outRes2; // bf16 dt[k5..k6] -> y[k6..k7] (k8 overwrites)

    // weight converts
    {
        int n;
        n = 2 * DIN_ * DM_; k_cvt<<<(n + 255) / 256, 256, 0, stream>>>(in_proj_w, inprojB, n);
        n = 96 * DIN_;      k_cvt<<<(n + 255) / 256, 256, 0, stream>>>(x_proj_w, xprojB, n);
        n = 32 * DIN_;      k_fill0<<<(n + 255) / 256, 256, 0, stream>>>(xprojB + 96 * DIN_, n);
        n = DIN_ * R_;      k_cvt<<<(n + 255) / 256, 256, 0, stream>>>(dt_proj_w, dtprojB, n);
        n = DM_ * DIN_;     k_cvt<<<(n + 255) / 256, 256, 0, stream>>>(out_proj_w, outprojB, n);
        n = 2 * H_ * DM_;   k_cvt<<<(n + 255) / 256, 256, 0, stream>>>(fc1_w, fc1B, n);
        n = DM_ * H_;       k_cvt<<<(n + 255) / 256, 256, 0, stream>>>(fc2_w, fc2B, n);
    }

    // 1) res = hs + residual ; hn = rmsnorm(res)
    k_add_rmsnorm<<<BL_, 256, 0, stream>>>(hs, resi, norm_w, resF, hnB);

    // 2) xz = hn @ in_proj^T   (M=8192, N=4096, K=1024)
    k_gemm<1><<<dim3(2 * DIN_ / 128, BL_ / 128), 256, 0, stream>>>(
        hnB, DM_, inprojB, DM_, (void*)xzB, 2 * DIN_, nullptr, BL_, 2 * DIN_, DM_, 2 * DIN_);

    // 3) depthwise conv + silu   (hn dead; xconv takes S_xc)
    k_conv_silu<<<(BL_ * DIN_ + 255) / 256, 256, 0, stream>>>(xzB, conv_w, conv_b, xconvB);

    // 4) dbl = x @ x_proj^T    (M=8192, N=128(pad), K=2048, store 96)
    k_gemm<1><<<dim3(1, BL_ / 128), 256, 0, stream>>>(
        xconvB, DIN_, xprojB, DIN_, (void*)dblB, 96, nullptr, BL_, 128, DIN_, 96);

    // 5) dt = softplus(dt_low @ dt_proj^T + b) -> bf16  (M=8192, N=2048, K=64)
    k_gemm<2><<<dim3(DIN_ / 128, BL_ / 128), 256, 0, stream>>>(
        dblB, 96, dtprojB, R_, (void*)dtyB, DIN_, dt_proj_b, BL_, DIN_, R_, DIN_);

    // 6) chunked selective scan (pass1 -> combine -> pass3); y overwrites dt in place
    k_scan_p1<<<dim3(B_ * (DIN_ / 256), CCH), 256, 0, stream>>>(
        dtyB, xconvB, dblB, A_log, scanQ, scanSd);
    k_scan_comb<<<(B_ * DIN_ * NS_) / 256, 256, 0, stream>>>(scanQ, scanSd, A_log);
    k_scan_p3<<<dim3(B_ * (DIN_ / 256), CCH), 256, 0, stream>>>(
        dtyB, xconvB, dblB, A_log, Dp, xzB, scanQ);

    // 7) mix = y @ out_proj^T  (M=8192, N=1024, K=2048)  (xconv dead; mixF takes S_xc)
    k_gemm<0><<<dim3(DM_ / 128, BL_ / 128), 256, 0, stream>>>(
        dtyB, DIN_, outprojB, DIN_, (void*)mixF, DM_, nullptr, BL_, DM_, DIN_, DM_);

    // 8) res2 = rmsnorm(mix + res) -> d_out[1] (overwrites dty scratch); mixB = bf16(mix)
    k_add_rmsnorm2<<<BL_, 256, 0, stream>>>(mixF, resF, norm2_w, outRes2, mixB);

    // 9) fc = mix @ fc1^T      (M=8192, N=2048, K=1024)  (xz dead; fc takes S_xz)
    k_gemm<1><<<dim3(2 * H_ / 128, BL_ / 128), 256, 0, stream>>>(
        mixB, DM_, fc1B, DM_, (void*)fcB, 2 * H_, nullptr, BL_, 2 * H_, DM_, 2 * H_);

    // 10) g = y * silu(gate)
    k_gate<<<(BL_ * H_ + 255) / 256, 256, 0, stream>>>(fcB, gB);

    // 11) out = g @ fc2^T      (M=8192, N=1024, K=1024) -> d_out[0] (overwrites res)
    k_gemm<0><<<dim3(DM_ / 128, BL_ / 128), 256, 0, stream>>>(
        gB, H_, fc2B, H_, (void*)outMain, DM_, nullptr, BL_, DM_, H_, DM_);
}

// Round 4
// 643.845 us; speedup vs baseline: 3.0926x; 1.0407x over previous
//
#include <hip/hip_runtime.h>
#include <hip/hip_bf16.h>

#define B_   4
#define L_   2048
#define DM_  1024
#define DIN_ 2048
#define NS_  16
#define R_   64
#define KC_  4
#define H_   1024
#define BL_  (B_ * L_)   // 8192 tokens
#define CCH  16          // scan chunks
#define CHL  (L_ / CCH)  // 128 steps per chunk

typedef __attribute__((ext_vector_type(4))) float f32x4;
typedef __attribute__((ext_vector_type(8))) short bf16x8;
typedef __attribute__((ext_vector_type(8))) unsigned short u16x8;

__device__ __forceinline__ float b2f(unsigned short u) {
    union { unsigned int i; float f; } v; v.i = ((unsigned int)u) << 16; return v.f;
}
__device__ __forceinline__ unsigned short f2b(float f) {
    union { float f; unsigned int i; } v; v.f = f;
    unsigned int r = v.i + 0x7fffu + ((v.i >> 16) & 1u);
    return (unsigned short)(r >> 16);
}
__device__ __forceinline__ float sigmoidf_(float x) { return 1.f / (1.f + __expf(-x)); }
__device__ __forceinline__ float softplusf_(float x) { return (x > 20.f) ? x : log1pf(__expf(x)); }

__device__ __forceinline__ void gload16(const unsigned short* g, unsigned short* l) {
    __builtin_amdgcn_global_load_lds(
        (__attribute__((address_space(1))) void*)(g),
        (__attribute__((address_space(3))) void*)(l), 16, 0, 0);
}

// ---------------- small elementwise kernels ----------------
__global__ void k_cvt(const float* __restrict__ in, unsigned short* __restrict__ out, int n) {
    int i = blockIdx.x * blockDim.x + threadIdx.x;
    if (i < n) out[i] = f2b(in[i]);
}
__global__ void k_fill0(unsigned short* __restrict__ out, int n) {
    int i = blockIdx.x * blockDim.x + threadIdx.x;
    if (i < n) out[i] = 0;
}

// res = a + b (fp32 out), hn = bf16(rmsnorm(res) * w)
__global__ __launch_bounds__(256)
void k_add_rmsnorm(const float* __restrict__ a, const float* __restrict__ b,
                   const float* __restrict__ w,
                   float* __restrict__ resOut, unsigned short* __restrict__ hnOut) {
    int row = blockIdx.x, tid = threadIdx.x;
    const float4* ap = (const float4*)(a + (size_t)row * DM_);
    const float4* bp = (const float4*)(b + (size_t)row * DM_);
    float4 va = ap[tid], vb = bp[tid];
    float4 s = make_float4(va.x + vb.x, va.y + vb.y, va.z + vb.z, va.w + vb.w);
    ((float4*)(resOut + (size_t)row * DM_))[tid] = s;
    float ss = s.x * s.x + s.y * s.y + s.z * s.z + s.w * s.w;
    #pragma unroll
    for (int m = 32; m >= 1; m >>= 1) ss += __shfl_xor(ss, m);
    __shared__ float red[4];
    if ((tid & 63) == 0) red[tid >> 6] = ss;
    __syncthreads();
    float tot = red[0] + red[1] + red[2] + red[3];
    float sc = rsqrtf(tot / (float)DM_ + 1e-5f);
    float4 vw = ((const float4*)w)[tid];
    unsigned short* hp = hnOut + (size_t)row * DM_ + tid * 4;
    *(ushort4*)hp = make_ushort4(f2b(s.x * sc * vw.x), f2b(s.y * sc * vw.y),
                                 f2b(s.z * sc * vw.z), f2b(s.w * sc * vw.w));
}

// res2 = rmsnorm(mix + res) * w (fp32 out), mixB = bf16(mix)
__global__ __launch_bounds__(256)
void k_add_rmsnorm2(const float* __restrict__ mix, const float* __restrict__ res,
                    const float* __restrict__ w,
                    float* __restrict__ res2Out, unsigned short* __restrict__ mixB) {
    int row = blockIdx.x, tid = threadIdx.x;
    const float4* mp = (const float4*)(mix + (size_t)row * DM_);
    const float4* rp = (const float4*)(res + (size_t)row * DM_);
    float4 vm = mp[tid], vr = rp[tid];
    float4 s = make_float4(vm.x + vr.x, vm.y + vr.y, vm.z + vr.z, vm.w + vr.w);
    unsigned short* mb = mixB + (size_t)row * DM_ + tid * 4;
    *(ushort4*)mb = make_ushort4(f2b(vm.x), f2b(vm.y), f2b(vm.z), f2b(vm.w));
    float ss = s.x * s.x + s.y * s.y + s.z * s.z + s.w * s.w;
    #pragma unroll
    for (int m = 32; m >= 1; m >>= 1) ss += __shfl_xor(ss, m);
    __shared__ float red[4];
    if ((tid & 63) == 0) red[tid >> 6] = ss;
    __syncthreads();
    float tot = red[0] + red[1] + red[2] + red[3];
    float sc = rsqrtf(tot / (float)DM_ + 1e-5f);
    float4 vw = ((const float4*)w)[tid];
    float4 o = make_float4(s.x * sc * vw.x, s.y * sc * vw.y, s.z * sc * vw.z, s.w * sc * vw.w);
    ((float4*)(res2Out + (size_t)row * DM_))[tid] = o;
}

// depthwise causal conv K=4 + bias + silu; x part of xz (cols [0,DIN))
__global__ void k_conv_silu(const unsigned short* __restrict__ xz,
                            const float* __restrict__ cw, const float* __restrict__ cb,
                            unsigned short* __restrict__ xc) {
    int i = blockIdx.x * blockDim.x + threadIdx.x;
    if (i >= BL_ * DIN_) return;
    int d = i % DIN_;
    int t = (i / DIN_) % L_;
    int b = i / (DIN_ * L_);
    const unsigned short* xrow = xz + (size_t)b * L_ * (2 * DIN_) + d;
    float acc = cb[d];
    #pragma unroll
    for (int k = 0; k < KC_; k++) {
        int tt = t - (KC_ - 1) + k;
        if (tt >= 0) acc += b2f(xrow[(size_t)tt * (2 * DIN_)]) * cw[d * KC_ + k];
    }
    xc[i] = f2b(acc * sigmoidf_(acc));
}

// g = y * silu(gate) from fc = [y | gate]
__global__ void k_gate(const unsigned short* __restrict__ fc, unsigned short* __restrict__ g) {
    int i = blockIdx.x * blockDim.x + threadIdx.x;
    if (i >= BL_ * H_) return;
    int h = i % H_;
    int row = i / H_;
    float y = b2f(fc[(size_t)row * (2 * H_) + h]);
    float gt = b2f(fc[(size_t)row * (2 * H_) + H_ + h]);
    g[i] = f2b(y * gt * sigmoidf_(gt));
}

// ---------------- chunked selective scan ----------------
__global__ __launch_bounds__(256)
void k_scan_p1(const unsigned short* __restrict__ dty, const unsigned short* __restrict__ xc,
               const unsigned short* __restrict__ dbl, const float* __restrict__ A_log,
               float* __restrict__ Q, float* __restrict__ sumdt) {
    __shared__ float Bs[64][NS_];
    const int tid = threadIdx.x;
    const int d = (blockIdx.x & 7) * 256 + tid;
    const int b = blockIdx.x >> 3;
    const int c = blockIdx.y;
    const int t0 = c * CHL;

    float a[NS_], h[NS_];
    #pragma unroll
    for (int n = 0; n < NS_; n++) { a[n] = -__expf(A_log[d * NS_ + n]); h[n] = 0.f; }
    float sd = 0.f;

    const unsigned short* dp  = dty + (size_t)b * L_ * DIN_ + d;
    const unsigned short* xp  = xc  + (size_t)b * L_ * DIN_ + d;
    const unsigned short* blp = dbl + (size_t)b * L_ * 96;

    for (int tt = 0; tt < CHL; tt += 64) {
        __syncthreads();
        if (tid < 128) {
            int r = tid >> 1, seg = tid & 1;
            u16x8 v = *(const u16x8*)(blp + (size_t)(t0 + tt + r) * 96 + 64 + seg * 8);
            #pragma unroll
            for (int j = 0; j < 8; j++) Bs[r][seg * 8 + j] = b2f(v[j]);
        }
        __syncthreads();
        #pragma unroll 2
        for (int t = 0; t < 64; t++) {
            int tg = t0 + tt + t;
            float dtv = b2f(dp[(size_t)tg * DIN_]);
            float xv  = b2f(xp[(size_t)tg * DIN_]);
            sd += dtv;
            float bx = dtv * xv;
            #pragma unroll
            for (int n = 0; n < NS_; n++)
                h[n] = __expf(dtv * a[n]) * h[n] + bx * Bs[t][n];
        }
    }
    float* q = Q + ((size_t)(b * CCH + c) * DIN_ + d) * NS_;
    #pragma unroll
    for (int s = 0; s < 4; s++)
        ((f32x4*)q)[s] = (f32x4){h[s*4], h[s*4+1], h[s*4+2], h[s*4+3]};
    sumdt[(size_t)(b * CCH + c) * DIN_ + d] = sd;
}

__global__ __launch_bounds__(256)
void k_scan_comb(float* __restrict__ Q, const float* __restrict__ sumdt,
                 const float* __restrict__ A_log) {
    int i = blockIdx.x * 256 + threadIdx.x;   // (b,d,n), 131072 total
    int n = i & 15;
    int d = (i >> 4) & (DIN_ - 1);
    int b = i >> 15;
    float a = -__expf(A_log[d * NS_ + n]);
    float h = 0.f;
    for (int c = 0; c < CCH; c++) {
        size_t base = ((size_t)(b * CCH + c) * DIN_ + d);
        float q  = Q[base * NS_ + n];
        float sd = sumdt[base];
        if (c > 0) Q[((size_t)(b * CCH + c - 1) * DIN_ + d) * NS_ + n] = h;
        h = __expf(a * sd) * h + q;
    }
}

__global__ __launch_bounds__(256)
void k_scan_p3(unsigned short* __restrict__ dty, const unsigned short* __restrict__ xc,
               const unsigned short* __restrict__ dbl, const float* __restrict__ A_log,
               const float* __restrict__ Dp, const unsigned short* __restrict__ xz,
               const float* __restrict__ Qh) {
    __shared__ float BCs[64][32];
    const int tid = threadIdx.x;
    const int d = (blockIdx.x & 7) * 256 + tid;
    const int b = blockIdx.x >> 3;
    const int c = blockIdx.y;
    const int t0 = c * CHL;

    float a[NS_], h[NS_];
    #pragma unroll
    for (int n = 0; n < NS_; n++) a[n] = -__expf(A_log[d * NS_ + n]);
    if (c == 0) {
        #pragma unroll
        for (int n = 0; n < NS_; n++) h[n] = 0.f;
    } else {
        const float* qh = Qh + ((size_t)(b * CCH + c - 1) * DIN_ + d) * NS_;
        #pragma unroll
        for (int s = 0; s < 4; s++) {
            f32x4 v = ((const f32x4*)qh)[s];
            h[s*4] = v[0]; h[s*4+1] = v[1]; h[s*4+2] = v[2]; h[s*4+3] = v[3];
        }
    }
    float Dd = Dp[d];

    unsigned short* dp = dty + (size_t)b * L_ * DIN_ + d;
    const unsigned short* xp  = xc + (size_t)b * L_ * DIN_ + d;
    const unsigned short* zp  = xz + (size_t)b * L_ * (2 * DIN_) + DIN_ + d;
    const unsigned short* blp = dbl + (size_t)b * L_ * 96;

    for (int tt = 0; tt < CHL; tt += 64) {
        __syncthreads();
        {
            int r = tid >> 2, seg = tid & 3;
            u16x8 v = *(const u16x8*)(blp + (size_t)(t0 + tt + r) * 96 + 64 + seg * 8);
            #pragma unroll
            for (int j = 0; j < 8; j++) BCs[r][seg * 8 + j] = b2f(v[j]);
        }
        __syncthreads();
        #pragma unroll 2
        for (int t = 0; t < 64; t++) {
            int tg = t0 + tt + t;
            float dtv = b2f(dp[(size_t)tg * DIN_]);
            float xv  = b2f(xp[(size_t)tg * DIN_]);
            float bx = dtv * xv;
            float y = 0.f;
            #pragma unroll
            for (int n = 0; n < NS_; n++) {
                h[n] = __expf(dtv * a[n]) * h[n] + bx * BCs[t][n];
                y += h[n] * BCs[t][16 + n];
            }
            y += xv * Dd;
            float zv = b2f(zp[(size_t)tg * (2 * DIN_)]);
            dp[(size_t)tg * DIN_] = f2b(y * zv * sigmoidf_(zv));
        }
    }
}

// ---------------- GEMM 128x128 (m97 structure) for small shapes ----------------
// EPI: 0 = fp32 store, 1 = bf16 store, 2 = bias + softplus + bf16 store
template <int EPI>
__global__ __launch_bounds__(256)
void k_gemm(const unsigned short* __restrict__ A, int lda,
            const unsigned short* __restrict__ Bw, int ldb,
            void* __restrict__ outp, int ldc, const float* __restrict__ bias,
            int M, int N, int Kd, int Nstore) {
    __shared__ unsigned short As[128 * 32];
    __shared__ unsigned short Bs[128 * 32];
    const int tid = threadIdx.x;
    const int lane = tid & 63;
    const int w = tid >> 6;
    const int wr = w >> 1, wc = w & 1;
    const int bm = blockIdx.y * 128, bn = blockIdx.x * 128;

    const int e0 = tid * 8;
    const int r0 = e0 >> 5;
    const int c0 = e0 & 31;
    const int r1 = r0 + 64;

    f32x4 acc[4][4];
    #pragma unroll
    for (int i = 0; i < 4; i++)
        #pragma unroll
        for (int j = 0; j < 4; j++) acc[i][j] = (f32x4){0.f, 0.f, 0.f, 0.f};

    const int fr = lane & 15, ko = (lane >> 4) * 8;

    for (int k0 = 0; k0 < Kd; k0 += 32) {
        gload16(A  + (size_t)(bm + r0) * lda + k0 + c0, &As[e0]);
        gload16(A  + (size_t)(bm + r1) * lda + k0 + c0, &As[e0 + 2048]);
        gload16(Bw + (size_t)(bn + r0) * ldb + k0 + c0, &Bs[e0]);
        gload16(Bw + (size_t)(bn + r1) * ldb + k0 + c0, &Bs[e0 + 2048]);
        __syncthreads();
        bf16x8 af[4], bv[4];
        #pragma unroll
        for (int i = 0; i < 4; i++)
            af[i] = *(const bf16x8*)&As[(wr * 64 + i * 16 + fr) * 32 + ko];
        #pragma unroll
        for (int j = 0; j < 4; j++)
            bv[j] = *(const bf16x8*)&Bs[(wc * 64 + j * 16 + fr) * 32 + ko];
        #pragma unroll
        for (int i = 0; i < 4; i++)
            #pragma unroll
            for (int j = 0; j < 4; j++)
                acc[i][j] = __builtin_amdgcn_mfma_f32_16x16x32_bf16(af[i], bv[j], acc[i][j], 0, 0, 0);
        __syncthreads();
    }

    const int rr = (lane >> 4) * 4;
    const int cc = lane & 15;
    #pragma unroll
    for (int i = 0; i < 4; i++) {
        #pragma unroll
        for (int j = 0; j < 4; j++) {
            int col = bn + wc * 64 + j * 16 + cc;
            if (col >= Nstore) continue;
            #pragma unroll
            for (int q = 0; q < 4; q++) {
                int row = bm + wr * 64 + i * 16 + rr + q;
                float v = acc[i][j][q];
                if constexpr (EPI == 2) { v += bias[col]; v = softplusf_(v); }
                if constexpr (EPI == 0)
                    ((float*)outp)[(size_t)row * ldc + col] = v;
                else
                    ((unsigned short*)outp)[(size_t)row * ldc + col] = f2b(v);
            }
        }
    }
}

// ---------------- GEMM 256x256, 8-wave, k-sliced LDS, counted-vmcnt pipeline ----
// C[M,N] = A[M,K] @ W[N,K]^T; M,N multiples of 256, K multiple of 128.
// LDS (dynamic 128KB): As[buf][ks][256*32], Bs likewise at +32768 elems.
// Swizzle: LDS[linear] holds global[linear ^ ((row&3)<<4 byte)]; reads XOR same.
#define SBAR   __builtin_amdgcn_s_barrier()
#define SCHED0 __builtin_amdgcn_sched_barrier(0)

template <int EPI>
__global__ __launch_bounds__(512, 2)
void k_gemm256(const unsigned short* __restrict__ Aptr, int lda,
               const unsigned short* __restrict__ Bptr, int ldb,
               void* __restrict__ outp, int ldc, int Kd) {
    extern __shared__ unsigned short lds[];
    const int tid  = threadIdx.x;
    const int lane = tid & 63;
    const int wid  = tid >> 6;
    const int wr = wid >> 2, wc = wid & 3;
    const int bm = blockIdx.y * 256, bn = blockIdx.x * 256;
    const int fr = lane & 15, sk = lane >> 4;

    f32x4 acc[8][4];
    #pragma unroll
    for (int i = 0; i < 8; i++)
        #pragma unroll
        for (int j = 0; j < 4; j++) acc[i][j] = (f32x4){0.f, 0.f, 0.f, 0.f};

    const int NT = Kd >> 6;

    // staging: thread covers two 16B chunks of each 16KB slice (512 thr * 2 * 16B)
    const int o0 = tid * 16, o1 = (512 + tid) * 16;       // byte offsets in slice
    const int sr0 = o0 >> 6, sr1 = o1 >> 6;               // slice row 0..255
    const int sc0 = (o0 & 63) ^ ((sr0 & 3) << 4);         // pre-swizzled source col byte
    const int sc1 = (o1 & 63) ^ ((sr1 & 3) << 4);
    const unsigned short* Ag0 = Aptr + (size_t)(bm + sr0) * lda + (sc0 >> 1);
    const unsigned short* Ag1 = Aptr + (size_t)(bm + sr1) * lda + (sc1 >> 1);
    const unsigned short* Bg0 = Bptr + (size_t)(bn + sr0) * ldb + (sc0 >> 1);
    const unsigned short* Bg1 = Bptr + (size_t)(bn + sr1) * ldb + (sc1 >> 1);
    unsigned short* L0 = lds + (o0 >> 1);
    unsigned short* L1 = lds + (o1 >> 1);

    auto stageA = [&](int buf, int ks, int kt) {
        int s = (buf * 2 + ks) * 8192;
        gload16(Ag0 + kt * 64 + ks * 32, L0 + s);
        gload16(Ag1 + kt * 64 + ks * 32, L1 + s);
    };
    auto stageB = [&](int buf, int ks, int kt) {
        int s = 32768 + (buf * 2 + ks) * 8192;
        gload16(Bg0 + kt * 64 + ks * 32, L0 + s);
        gload16(Bg1 + kt * 64 + ks * 32, L1 + s);
    };

    // ds-read offsets (swizzled): frag at (row, sk*16B ^ ((row&3)<<4)); row&3 == fr&3
    const int rsw  = (sk * 16) ^ ((fr & 3) << 4);
    const int aoff = (wr * 128 + fr) * 32 + (rsw >> 1);
    const int boff = (wc * 64  + fr) * 32 + (rsw >> 1);

#define DSREAD_B(buf, ks) { _Pragma("unroll") for (int n = 0; n < 4; n++) \
    bv[n] = *(const bf16x8*)&lds[32768 + ((buf)*2+(ks))*8192 + boff + n*512]; }
#define DSREAD_A(buf, ks, mh) { _Pragma("unroll") for (int m = 0; m < 4; m++) \
    af[m] = *(const bf16x8*)&lds[((buf)*2+(ks))*8192 + aoff + ((mh)*4+m)*512]; }
#define MFMA16(mh) { __builtin_amdgcn_s_setprio(1); \
    _Pragma("unroll") for (int m = 0; m < 4; m++) \
      _Pragma("unroll") for (int n = 0; n < 4; n++) \
        acc[(mh)*4+m][n] = __builtin_amdgcn_mfma_f32_16x16x32_bf16(af[m], bv[n], acc[(mh)*4+m][n], 0, 0, 0); \
    __builtin_amdgcn_s_setprio(0); }

    // prologue: stage k-tile 0 (order A0,B0,A1,B1), gate first two slices
    stageA(0, 0, 0); stageB(0, 0, 0); stageA(0, 1, 0); stageB(0, 1, 0);
    SCHED0;
    asm volatile("s_waitcnt vmcnt(4)" ::: "memory");
    SBAR;

    int buf = 0;
    for (int kt = 0; kt < NT - 1; ++kt) {
        bf16x8 af[4], bv[4];
        // phase 0: ks0, m-half 0
        DSREAD_B(buf, 0); DSREAD_A(buf, 0, 0);
        stageA(buf ^ 1, 0, kt + 1);
        SCHED0; SBAR;
        MFMA16(0);
        SCHED0; SBAR;
        // phase 1: ks0, m-half 1
        DSREAD_A(buf, 0, 1);
        stageB(buf ^ 1, 0, kt + 1);
        SCHED0; SBAR;
        MFMA16(1);
        SCHED0;
        asm volatile("s_waitcnt vmcnt(4)" ::: "memory");   // gate ks1(kt)
        SBAR;
        // phase 2: ks1, m-half 0
        DSREAD_B(buf, 1); DSREAD_A(buf, 1, 0);
        stageA(buf ^ 1, 1, kt + 1);
        SCHED0; SBAR;
        MFMA16(0);
        SCHED0; SBAR;
        // phase 3: ks1, m-half 1
        DSREAD_A(buf, 1, 1);
        stageB(buf ^ 1, 1, kt + 1);
        SCHED0; SBAR;
        MFMA16(1);
        SCHED0;
        asm volatile("s_waitcnt vmcnt(4)" ::: "memory");   // gate ks0(kt+1)
        SBAR;
        buf ^= 1;
    }
    {   // epilogue K-tile (no staging; drain 4 -> 0)
        bf16x8 af[4], bv[4];
        DSREAD_B(buf, 0); DSREAD_A(buf, 0, 0);
        SCHED0; SBAR;
        MFMA16(0);
        SCHED0; SBAR;
        DSREAD_A(buf, 0, 1);
        SCHED0; SBAR;
        MFMA16(1);
        SCHED0;
        asm volatile("s_waitcnt vmcnt(0)" ::: "memory");
        SBAR;
        DSREAD_B(buf, 1); DSREAD_A(buf, 1, 0);
        SCHED0; SBAR;
        MFMA16(0);
        SCHED0; SBAR;
        DSREAD_A(buf, 1, 1);
        SCHED0; SBAR;
        MFMA16(1);
    }
#undef DSREAD_B
#undef DSREAD_A
#undef MFMA16

    const int rr = sk * 4;
    const int cc = fr;
    #pragma unroll
    for (int mf = 0; mf < 8; mf++) {
        #pragma unroll
        for (int nf = 0; nf < 4; nf++) {
            int col = bn + wc * 64 + nf * 16 + cc;
            #pragma unroll
            for (int q = 0; q < 4; q++) {
                int row = bm + wr * 128 + mf * 16 + rr + q;
                float v = acc[mf][nf][q];
                if constexpr (EPI == 0)
                    ((float*)outp)[(size_t)row * ldc + col] = v;
                else
                    ((unsigned short*)outp)[(size_t)row * ldc + col] = f2b(v);
            }
        }
    }
}

// ---------------- host ----------------
extern "C" void kernel_launch(void* const* d_in, const int* in_sizes, int n_in,
                              void* d_out, int out_size, void* d_ws, size_t ws_size,
                              hipStream_t stream) {
    const float* hs        = (const float*)d_in[0];
    const float* resi      = (const float*)d_in[1];
    const float* norm_w    = (const float*)d_in[2];
    const float* in_proj_w = (const float*)d_in[3];
    const float* conv_w    = (const float*)d_in[4];
    const float* conv_b    = (const float*)d_in[5];
    const float* x_proj_w  = (const float*)d_in[6];
    const float* dt_proj_w = (const float*)d_in[7];
    const float* dt_proj_b = (const float*)d_in[8];
    const float* A_log     = (const float*)d_in[9];
    const float* Dp        = (const float*)d_in[10];
    const float* out_proj_w= (const float*)d_in[11];
    const float* norm2_w   = (const float*)d_in[12];
    const float* fc1_w     = (const float*)d_in[13];
    const float* fc2_w     = (const float*)d_in[14];

    static bool attrDone = false;
    if (!attrDone) {
        hipFuncSetAttribute(reinterpret_cast<const void*>(k_gemm256<0>),
                            hipFuncAttributeMaxDynamicSharedMemorySize, 131072);
        hipFuncSetAttribute(reinterpret_cast<const void*>(k_gemm256<1>),
                            hipFuncAttributeMaxDynamicSharedMemorySize, 131072);
        attrDone = true;
    }

    char* ws = (char*)d_ws;
    size_t off = 0;
    auto alloc = [&](size_t bytes) {
        void* p = ws + off;
        off = (off + bytes + 255) & ~(size_t)255;
        return p;
    };

    // --- workspace overlay (total ~116 MB) ---
    unsigned short* xzB  = (unsigned short*)alloc((size_t)BL_ * 2 * DIN_ * 2);
    unsigned short* fcB  = xzB;                              // 32MB, [k9..k10]
    unsigned short* gB   = xzB + (size_t)BL_ * 2 * H_;       // 16MB, [k10..k11]
    unsigned short* mixB = gB  + (size_t)BL_ * H_;           // 16MB, [k8..k9]
    void* S_xc = alloc((size_t)BL_ * DIN_ * 2);
    unsigned short* hnB    = (unsigned short*)S_xc;
    unsigned short* xconvB = (unsigned short*)S_xc;
    float*          mixF   = (float*)S_xc;
    unsigned short* dblB = (unsigned short*)alloc((size_t)BL_ * 96 * 2);
    unsigned short* inprojB  = (unsigned short*)alloc((size_t)2 * DIN_ * DM_ * 2);  // dead after k2
    unsigned short* xprojB   = (unsigned short*)alloc((size_t)128 * DIN_ * 2);
    unsigned short* dtprojB  = (unsigned short*)alloc((size_t)DIN_ * R_ * 2);
    unsigned short* outprojB = (unsigned short*)alloc((size_t)DM_ * DIN_ * 2);
    unsigned short* fc1B     = (unsigned short*)alloc((size_t)2 * H_ * DM_ * 2);
    unsigned short* fc2B     = (unsigned short*)alloc((size_t)DM_ * H_ * 2);

    float* scanQ  = (float*)inprojB;
    float* scanSd = scanQ + (size_t)B_ * CCH * DIN_ * NS_;

    float* outMain = (float*)d_out;
    float* outRes2 = (float*)d_out + (size_t)BL_ * DM_;
    float*          resF = outMain;
    unsigned short* dtyB = (unsigned short*)outRes2;

    {
        int n;
        n = 2 * DIN_ * DM_; k_cvt<<<(n + 255) / 256, 256, 0, stream>>>(in_proj_w, inprojB, n);
        n = 96 * DIN_;      k_cvt<<<(n + 255) / 256, 256, 0, stream>>>(x_proj_w, xprojB, n);
        n = 32 * DIN_;      k_fill0<<<(n + 255) / 256, 256, 0, stream>>>(xprojB + 96 * DIN_, n);
        n = DIN_ * R_;      k_cvt<<<(n + 255) / 256, 256, 0, stream>>>(dt_proj_w, dtprojB, n);
        n = DM_ * DIN_;     k_cvt<<<(n + 255) / 256, 256, 0, stream>>>(out_proj_w, outprojB, n);
        n = 2 * H_ * DM_;   k_cvt<<<(n + 255) / 256, 256, 0, stream>>>(fc1_w, fc1B, n);
        n = DM_ * H_;       k_cvt<<<(n + 255) / 256, 256, 0, stream>>>(fc2_w, fc2B, n);
    }

    // 1) res = hs + residual ; hn = rmsnorm(res)
    k_add_rmsnorm<<<BL_, 256, 0, stream>>>(hs, resi, norm_w, resF, hnB);

    // 2) xz = hn @ in_proj^T   (M=8192, N=4096, K=1024)
    k_gemm256<1><<<dim3(2 * DIN_ / 256, BL_ / 256), 512, 131072, stream>>>(
        hnB, DM_, inprojB, DM_, (void*)xzB, 2 * DIN_, DM_);

    // 3) depthwise conv + silu
    k_conv_silu<<<(BL_ * DIN_ + 255) / 256, 256, 0, stream>>>(xzB, conv_w, conv_b, xconvB);

    // 4) dbl = x @ x_proj^T    (M=8192, N=128(pad), K=2048, store 96)
    k_gemm<1><<<dim3(1, BL_ / 128), 256, 0, stream>>>(
        xconvB, DIN_, xprojB, DIN_, (void*)dblB, 96, nullptr, BL_, 128, DIN_, 96);

    // 5) dt = softplus(dt_low @ dt_proj^T + b) -> bf16  (M=8192, N=2048, K=64)
    k_gemm<2><<<dim3(DIN_ / 128, BL_ / 128), 256, 0, stream>>>(
        dblB, 96, dtprojB, R_, (void*)dtyB, DIN_, dt_proj_b, BL_, DIN_, R_, DIN_);

    // 6) chunked selective scan
    k_scan_p1<<<dim3(B_ * (DIN_ / 256), CCH), 256, 0, stream>>>(
        dtyB, xconvB, dblB, A_log, scanQ, scanSd);
    k_scan_comb<<<(B_ * DIN_ * NS_) / 256, 256, 0, stream>>>(scanQ, scanSd, A_log);
    k_scan_p3<<<dim3(B_ * (DIN_ / 256), CCH), 256, 0, stream>>>(
        dtyB, xconvB, dblB, A_log, Dp, xzB, scanQ);

    // 7) mix = y @ out_proj^T  (M=8192, N=1024, K=2048)
    k_gemm256<0><<<dim3(DM_ / 256, BL_ / 256), 512, 131072, stream>>>(
        dtyB, DIN_, outprojB, DIN_, (void*)mixF, DM_, DIN_);

    // 8) res2 = rmsnorm(mix + res) -> d_out[1]; mixB = bf16(mix)
    k_add_rmsnorm2<<<BL_, 256, 0, stream>>>(mixF, resF, norm2_w, outRes2, mixB);

    // 9) fc = mix @ fc1^T      (M=8192, N=2048, K=1024)
    k_gemm256<1><<<dim3(2 * H_ / 256, BL_ / 256), 512, 131072, stream>>>(
        mixB, DM_, fc1B, DM_, (void*)fcB, 2 * H_, DM_);

    // 10) g = y * silu(gate)
    k_gate<<<(BL_ * H_ + 255) / 256, 256, 0, stream>>>(fcB, gB);

    // 11) out = g @ fc2^T      (M=8192, N=1024, K=1024) -> d_out[0]
    k_gemm256<0><<<dim3(DM_ / 256, BL_ / 256), 512, 131072, stream>>>(
        gB, H_, fc2B, H_, (void*)outMain, DM_, H_);
}

// Round 5
// 615.460 us; speedup vs baseline: 3.2352x; 1.0461x over previous
//
#include <hip/hip_runtime.h>
#include <hip/hip_bf16.h>

#define B_   4
#define L_   2048
#define DM_  1024
#define DIN_ 2048
#define NS_  16
#define R_   64
#define KC_  4
#define H_   1024
#define BL_  (B_ * L_)   // 8192 tokens
#define CCH  32          // scan chunks
#define CHL  (L_ / CCH)  // 64 steps per chunk

typedef __attribute__((ext_vector_type(4))) float f32x4;
typedef __attribute__((ext_vector_type(8))) short bf16x8;
typedef __attribute__((ext_vector_type(8))) unsigned short u16x8;

__device__ __forceinline__ float b2f(unsigned short u) {
    union { unsigned int i; float f; } v; v.i = ((unsigned int)u) << 16; return v.f;
}
__device__ __forceinline__ unsigned short f2b(float f) {
    union { float f; unsigned int i; } v; v.f = f;
    unsigned int r = v.i + 0x7fffu + ((v.i >> 16) & 1u);
    return (unsigned short)(r >> 16);
}
__device__ __forceinline__ float sigmoidf_(float x) { return 1.f / (1.f + __expf(-x)); }
__device__ __forceinline__ float softplusf_(float x) { return (x > 20.f) ? x : log1pf(__expf(x)); }

__device__ __forceinline__ void gload16(const unsigned short* g, unsigned short* l) {
    __builtin_amdgcn_global_load_lds(
        (__attribute__((address_space(1))) void*)(g),
        (__attribute__((address_space(3))) void*)(l), 16, 0, 0);
}

// ---------------- small elementwise kernels ----------------
__global__ void k_cvt(const float* __restrict__ in, unsigned short* __restrict__ out, int n) {
    int i = blockIdx.x * blockDim.x + threadIdx.x;
    if (i < n) out[i] = f2b(in[i]);
}
__global__ void k_fill0(unsigned short* __restrict__ out, int n) {
    int i = blockIdx.x * blockDim.x + threadIdx.x;
    if (i < n) out[i] = 0;
}

// res = a + b (fp32 out), hn = bf16(rmsnorm(res) * w)
__global__ __launch_bounds__(256)
void k_add_rmsnorm(const float* __restrict__ a, const float* __restrict__ b,
                   const float* __restrict__ w,
                   float* __restrict__ resOut, unsigned short* __restrict__ hnOut) {
    int row = blockIdx.x, tid = threadIdx.x;
    const float4* ap = (const float4*)(a + (size_t)row * DM_);
    const float4* bp = (const float4*)(b + (size_t)row * DM_);
    float4 va = ap[tid], vb = bp[tid];
    float4 s = make_float4(va.x + vb.x, va.y + vb.y, va.z + vb.z, va.w + vb.w);
    ((float4*)(resOut + (size_t)row * DM_))[tid] = s;
    float ss = s.x * s.x + s.y * s.y + s.z * s.z + s.w * s.w;
    #pragma unroll
    for (int m = 32; m >= 1; m >>= 1) ss += __shfl_xor(ss, m);
    __shared__ float red[4];
    if ((tid & 63) == 0) red[tid >> 6] = ss;
    __syncthreads();
    float tot = red[0] + red[1] + red[2] + red[3];
    float sc = rsqrtf(tot / (float)DM_ + 1e-5f);
    float4 vw = ((const float4*)w)[tid];
    unsigned short* hp = hnOut + (size_t)row * DM_ + tid * 4;
    *(ushort4*)hp = make_ushort4(f2b(s.x * sc * vw.x), f2b(s.y * sc * vw.y),
                                 f2b(s.z * sc * vw.z), f2b(s.w * sc * vw.w));
}

// res2 = rmsnorm(mix + res) * w (fp32 out), mixB = bf16(mix)
__global__ __launch_bounds__(256)
void k_add_rmsnorm2(const float* __restrict__ mix, const float* __restrict__ res,
                    const float* __restrict__ w,
                    float* __restrict__ res2Out, unsigned short* __restrict__ mixB) {
    int row = blockIdx.x, tid = threadIdx.x;
    const float4* mp = (const float4*)(mix + (size_t)row * DM_);
    const float4* rp = (const float4*)(res + (size_t)row * DM_);
    float4 vm = mp[tid], vr = rp[tid];
    float4 s = make_float4(vm.x + vr.x, vm.y + vr.y, vm.z + vr.z, vm.w + vr.w);
    unsigned short* mb = mixB + (size_t)row * DM_ + tid * 4;
    *(ushort4*)mb = make_ushort4(f2b(vm.x), f2b(vm.y), f2b(vm.z), f2b(vm.w));
    float ss = s.x * s.x + s.y * s.y + s.z * s.z + s.w * s.w;
    #pragma unroll
    for (int m = 32; m >= 1; m >>= 1) ss += __shfl_xor(ss, m);
    __shared__ float red[4];
    if ((tid & 63) == 0) red[tid >> 6] = ss;
    __syncthreads();
    float tot = red[0] + red[1] + red[2] + red[3];
    float sc = rsqrtf(tot / (float)DM_ + 1e-5f);
    float4 vw = ((const float4*)w)[tid];
    float4 o = make_float4(s.x * sc * vw.x, s.y * sc * vw.y, s.z * sc * vw.z, s.w * sc * vw.w);
    ((float4*)(res2Out + (size_t)row * DM_))[tid] = o;
}

// depthwise causal conv K=4 + bias + silu; x part of xz (cols [0,DIN))
__global__ void k_conv_silu(const unsigned short* __restrict__ xz,
                            const float* __restrict__ cw, const float* __restrict__ cb,
                            unsigned short* __restrict__ xc) {
    int i = blockIdx.x * blockDim.x + threadIdx.x;
    if (i >= BL_ * DIN_) return;
    int d = i % DIN_;
    int t = (i / DIN_) % L_;
    int b = i / (DIN_ * L_);
    const unsigned short* xrow = xz + (size_t)b * L_ * (2 * DIN_) + d;
    float acc = cb[d];
    #pragma unroll
    for (int k = 0; k < KC_; k++) {
        int tt = t - (KC_ - 1) + k;
        if (tt >= 0) acc += b2f(xrow[(size_t)tt * (2 * DIN_)]) * cw[d * KC_ + k];
    }
    xc[i] = f2b(acc * sigmoidf_(acc));
}

// g = y * silu(gate) from fc = [y | gate]
__global__ void k_gate(const unsigned short* __restrict__ fc, unsigned short* __restrict__ g) {
    int i = blockIdx.x * blockDim.x + threadIdx.x;
    if (i >= BL_ * H_) return;
    int h = i % H_;
    int row = i / H_;
    float y = b2f(fc[(size_t)row * (2 * H_) + h]);
    float gt = b2f(fc[(size_t)row * (2 * H_) + H_ + h]);
    g[i] = f2b(y * gt * sigmoidf_(gt));
}

// ---------------- chunked selective scan ----------------
// Thread-per-channel; CCH chunks of CHL steps. Q/sumdt stored bf16.
__global__ __launch_bounds__(256)
void k_scan_p1(const unsigned short* __restrict__ dty, const unsigned short* __restrict__ xc,
               const unsigned short* __restrict__ dbl, const float* __restrict__ A_log,
               unsigned short* __restrict__ Q, unsigned short* __restrict__ sumdt) {
    __shared__ float Bs[64][NS_];
    const int tid = threadIdx.x;
    const int d = (blockIdx.x & 7) * 256 + tid;
    const int b = blockIdx.x >> 3;
    const int c = blockIdx.y;
    const int t0 = c * CHL;

    float a[NS_], h[NS_];
    #pragma unroll
    for (int n = 0; n < NS_; n++) { a[n] = -__expf(A_log[d * NS_ + n]); h[n] = 0.f; }
    float sd = 0.f;

    const unsigned short* dp  = dty + (size_t)b * L_ * DIN_ + d;
    const unsigned short* xp  = xc  + (size_t)b * L_ * DIN_ + d;
    const unsigned short* blp = dbl + (size_t)b * L_ * 96;

    for (int tt = 0; tt < CHL; tt += 64) {
        __syncthreads();
        if (tid < 128) {
            int r = tid >> 1, seg = tid & 1;
            u16x8 v = *(const u16x8*)(blp + (size_t)(t0 + tt + r) * 96 + 64 + seg * 8);
            #pragma unroll
            for (int j = 0; j < 8; j++) Bs[r][seg * 8 + j] = b2f(v[j]);
        }
        __syncthreads();
        #pragma unroll 2
        for (int t = 0; t < 64; t++) {
            int tg = t0 + tt + t;
            float dtv = b2f(dp[(size_t)tg * DIN_]);
            float xv  = b2f(xp[(size_t)tg * DIN_]);
            sd += dtv;
            float bx = dtv * xv;
            #pragma unroll
            for (int n = 0; n < NS_; n++)
                h[n] = __expf(dtv * a[n]) * h[n] + bx * Bs[t][n];
        }
    }
    unsigned short* q = Q + ((size_t)(b * CCH + c) * DIN_ + d) * NS_;
    u16x8 qa, qb;
    #pragma unroll
    for (int j = 0; j < 8; j++) { qa[j] = f2b(h[j]); qb[j] = f2b(h[8 + j]); }
    *(u16x8*)q = qa;
    *(u16x8*)(q + 8) = qb;
    sumdt[(size_t)(b * CCH + c) * DIN_ + d] = f2b(sd);
}

__global__ __launch_bounds__(256)
void k_scan_comb(unsigned short* __restrict__ Q, const unsigned short* __restrict__ sumdt,
                 const float* __restrict__ A_log) {
    int i = blockIdx.x * 256 + threadIdx.x;   // (b,d,n), 131072 total
    int n = i & 15;
    int d = (i >> 4) & (DIN_ - 1);
    int b = i >> 15;
    float a = -__expf(A_log[d * NS_ + n]);
    float h = 0.f;
    for (int c = 0; c < CCH; c++) {
        size_t base = ((size_t)(b * CCH + c) * DIN_ + d);
        float q  = b2f(Q[base * NS_ + n]);
        float sd = b2f(sumdt[base]);
        if (c > 0) Q[((size_t)(b * CCH + c - 1) * DIN_ + d) * NS_ + n] = f2b(h);
        h = __expf(a * sd) * h + q;
    }
}

__global__ __launch_bounds__(256)
void k_scan_p3(unsigned short* __restrict__ dty, const unsigned short* __restrict__ xc,
               const unsigned short* __restrict__ dbl, const float* __restrict__ A_log,
               const float* __restrict__ Dp, const unsigned short* __restrict__ xz,
               const unsigned short* __restrict__ Qh) {
    __shared__ float BCs[64][32];
    const int tid = threadIdx.x;
    const int d = (blockIdx.x & 7) * 256 + tid;
    const int b = blockIdx.x >> 3;
    const int c = blockIdx.y;
    const int t0 = c * CHL;

    float a[NS_], h[NS_];
    #pragma unroll
    for (int n = 0; n < NS_; n++) a[n] = -__expf(A_log[d * NS_ + n]);
    if (c == 0) {
        #pragma unroll
        for (int n = 0; n < NS_; n++) h[n] = 0.f;
    } else {
        const unsigned short* qh = Qh + ((size_t)(b * CCH + c - 1) * DIN_ + d) * NS_;
        u16x8 v0 = *(const u16x8*)qh;
        u16x8 v1 = *(const u16x8*)(qh + 8);
        #pragma unroll
        for (int j = 0; j < 8; j++) { h[j] = b2f(v0[j]); h[8 + j] = b2f(v1[j]); }
    }
    float Dd = Dp[d];

    unsigned short* dp = dty + (size_t)b * L_ * DIN_ + d;
    const unsigned short* xp  = xc + (size_t)b * L_ * DIN_ + d;
    const unsigned short* zp  = xz + (size_t)b * L_ * (2 * DIN_) + DIN_ + d;
    const unsigned short* blp = dbl + (size_t)b * L_ * 96;

    for (int tt = 0; tt < CHL; tt += 64) {
        __syncthreads();
        {
            int r = tid >> 2, seg = tid & 3;
            u16x8 v = *(const u16x8*)(blp + (size_t)(t0 + tt + r) * 96 + 64 + seg * 8);
            #pragma unroll
            for (int j = 0; j < 8; j++) BCs[r][seg * 8 + j] = b2f(v[j]);
        }
        __syncthreads();
        #pragma unroll 2
        for (int t = 0; t < 64; t++) {
            int tg = t0 + tt + t;
            float dtv = b2f(dp[(size_t)tg * DIN_]);
            float xv  = b2f(xp[(size_t)tg * DIN_]);
            float bx = dtv * xv;
            float y = 0.f;
            #pragma unroll
            for (int n = 0; n < NS_; n++) {
                h[n] = __expf(dtv * a[n]) * h[n] + bx * BCs[t][n];
                y += h[n] * BCs[t][16 + n];
            }
            y += xv * Dd;
            float zv = b2f(zp[(size_t)tg * (2 * DIN_)]);
            dp[(size_t)tg * DIN_] = f2b(y * zv * sigmoidf_(zv));
        }
    }
}

// ---------------- GEMM 128x128 (m97 structure) for small shapes ----------------
// EPI: 0 = fp32 store, 1 = bf16 store, 2 = bias + softplus + bf16 store
template <int EPI>
__global__ __launch_bounds__(256)
void k_gemm(const unsigned short* __restrict__ A, int lda,
            const unsigned short* __restrict__ Bw, int ldb,
            void* __restrict__ outp, int ldc, const float* __restrict__ bias,
            int M, int N, int Kd, int Nstore) {
    __shared__ unsigned short As[128 * 32];
    __shared__ unsigned short Bs[128 * 32];
    const int tid = threadIdx.x;
    const int lane = tid & 63;
    const int w = tid >> 6;
    const int wr = w >> 1, wc = w & 1;
    const int bm = blockIdx.y * 128, bn = blockIdx.x * 128;

    const int e0 = tid * 8;
    const int r0 = e0 >> 5;
    const int c0 = e0 & 31;
    const int r1 = r0 + 64;

    f32x4 acc[4][4];
    #pragma unroll
    for (int i = 0; i < 4; i++)
        #pragma unroll
        for (int j = 0; j < 4; j++) acc[i][j] = (f32x4){0.f, 0.f, 0.f, 0.f};

    const int fr = lane & 15, ko = (lane >> 4) * 8;

    for (int k0 = 0; k0 < Kd; k0 += 32) {
        gload16(A  + (size_t)(bm + r0) * lda + k0 + c0, &As[e0]);
        gload16(A  + (size_t)(bm + r1) * lda + k0 + c0, &As[e0 + 2048]);
        gload16(Bw + (size_t)(bn + r0) * ldb + k0 + c0, &Bs[e0]);
        gload16(Bw + (size_t)(bn + r1) * ldb + k0 + c0, &Bs[e0 + 2048]);
        __syncthreads();
        bf16x8 af[4], bv[4];
        #pragma unroll
        for (int i = 0; i < 4; i++)
            af[i] = *(const bf16x8*)&As[(wr * 64 + i * 16 + fr) * 32 + ko];
        #pragma unroll
        for (int j = 0; j < 4; j++)
            bv[j] = *(const bf16x8*)&Bs[(wc * 64 + j * 16 + fr) * 32 + ko];
        #pragma unroll
        for (int i = 0; i < 4; i++)
            #pragma unroll
            for (int j = 0; j < 4; j++)
                acc[i][j] = __builtin_amdgcn_mfma_f32_16x16x32_bf16(af[i], bv[j], acc[i][j], 0, 0, 0);
        __syncthreads();
    }

    const int rr = (lane >> 4) * 4;
    const int cc = lane & 15;
    #pragma unroll
    for (int i = 0; i < 4; i++) {
        #pragma unroll
        for (int j = 0; j < 4; j++) {
            int col = bn + wc * 64 + j * 16 + cc;
            if (col >= Nstore) continue;
            #pragma unroll
            for (int q = 0; q < 4; q++) {
                int row = bm + wr * 64 + i * 16 + rr + q;
                float v = acc[i][j][q];
                if constexpr (EPI == 2) { v += bias[col]; v = softplusf_(v); }
                if constexpr (EPI == 0)
                    ((float*)outp)[(size_t)row * ldc + col] = v;
                else
                    ((unsigned short*)outp)[(size_t)row * ldc + col] = f2b(v);
            }
        }
    }
}

// ---------------- GEMM 256x256, 8-wave, k-sliced LDS, counted-vmcnt pipeline ----
#define SBAR   __builtin_amdgcn_s_barrier()
#define SCHED0 __builtin_amdgcn_sched_barrier(0)

template <int EPI>
__global__ __launch_bounds__(512, 2)
void k_gemm256(const unsigned short* __restrict__ Aptr, int lda,
               const unsigned short* __restrict__ Bptr, int ldb,
               void* __restrict__ outp, int ldc, int Kd) {
    extern __shared__ unsigned short lds[];
    const int tid  = threadIdx.x;
    const int lane = tid & 63;
    const int wid  = tid >> 6;
    const int wr = wid >> 2, wc = wid & 3;
    const int bm = blockIdx.y * 256, bn = blockIdx.x * 256;
    const int fr = lane & 15, sk = lane >> 4;

    f32x4 acc[8][4];
    #pragma unroll
    for (int i = 0; i < 8; i++)
        #pragma unroll
        for (int j = 0; j < 4; j++) acc[i][j] = (f32x4){0.f, 0.f, 0.f, 0.f};

    const int NT = Kd >> 6;

    const int o0 = tid * 16, o1 = (512 + tid) * 16;
    const int sr0 = o0 >> 6, sr1 = o1 >> 6;
    const int sc0 = (o0 & 63) ^ ((sr0 & 3) << 4);
    const int sc1 = (o1 & 63) ^ ((sr1 & 3) << 4);
    const unsigned short* Ag0 = Aptr + (size_t)(bm + sr0) * lda + (sc0 >> 1);
    const unsigned short* Ag1 = Aptr + (size_t)(bm + sr1) * lda + (sc1 >> 1);
    const unsigned short* Bg0 = Bptr + (size_t)(bn + sr0) * ldb + (sc0 >> 1);
    const unsigned short* Bg1 = Bptr + (size_t)(bn + sr1) * ldb + (sc1 >> 1);
    unsigned short* L0 = lds + (o0 >> 1);
    unsigned short* L1 = lds + (o1 >> 1);

    auto stageA = [&](int buf, int ks, int kt) {
        int s = (buf * 2 + ks) * 8192;
        gload16(Ag0 + kt * 64 + ks * 32, L0 + s);
        gload16(Ag1 + kt * 64 + ks * 32, L1 + s);
    };
    auto stageB = [&](int buf, int ks, int kt) {
        int s = 32768 + (buf * 2 + ks) * 8192;
        gload16(Bg0 + kt * 64 + ks * 32, L0 + s);
        gload16(Bg1 + kt * 64 + ks * 32, L1 + s);
    };

    const int rsw  = (sk * 16) ^ ((fr & 3) << 4);
    const int aoff = (wr * 128 + fr) * 32 + (rsw >> 1);
    const int boff = (wc * 64  + fr) * 32 + (rsw >> 1);

#define DSREAD_B(buf, ks) { _Pragma("unroll") for (int n = 0; n < 4; n++) \
    bv[n] = *(const bf16x8*)&lds[32768 + ((buf)*2+(ks))*8192 + boff + n*512]; }
#define DSREAD_A(buf, ks, mh) { _Pragma("unroll") for (int m = 0; m < 4; m++) \
    af[m] = *(const bf16x8*)&lds[((buf)*2+(ks))*8192 + aoff + ((mh)*4+m)*512]; }
#define MFMA16(mh) { __builtin_amdgcn_s_setprio(1); \
    _Pragma("unroll") for (int m = 0; m < 4; m++) \
      _Pragma("unroll") for (int n = 0; n < 4; n++) \
        acc[(mh)*4+m][n] = __builtin_amdgcn_mfma_f32_16x16x32_bf16(af[m], bv[n], acc[(mh)*4+m][n], 0, 0, 0); \
    __builtin_amdgcn_s_setprio(0); }

    stageA(0, 0, 0); stageB(0, 0, 0); stageA(0, 1, 0); stageB(0, 1, 0);
    SCHED0;
    asm volatile("s_waitcnt vmcnt(4)" ::: "memory");
    SBAR;

    int buf = 0;
    for (int kt = 0; kt < NT - 1; ++kt) {
        bf16x8 af[4], bv[4];
        DSREAD_B(buf, 0); DSREAD_A(buf, 0, 0);
        stageA(buf ^ 1, 0, kt + 1);
        SCHED0; SBAR;
        MFMA16(0);
        SCHED0; SBAR;
        DSREAD_A(buf, 0, 1);
        stageB(buf ^ 1, 0, kt + 1);
        SCHED0; SBAR;
        MFMA16(1);
        SCHED0;
        asm volatile("s_waitcnt vmcnt(4)" ::: "memory");
        SBAR;
        DSREAD_B(buf, 1); DSREAD_A(buf, 1, 0);
        stageA(buf ^ 1, 1, kt + 1);
        SCHED0; SBAR;
        MFMA16(0);
        SCHED0; SBAR;
        DSREAD_A(buf, 1, 1);
        stageB(buf ^ 1, 1, kt + 1);
        SCHED0; SBAR;
        MFMA16(1);
        SCHED0;
        asm volatile("s_waitcnt vmcnt(4)" ::: "memory");
        SBAR;
        buf ^= 1;
    }
    {
        bf16x8 af[4], bv[4];
        DSREAD_B(buf, 0); DSREAD_A(buf, 0, 0);
        SCHED0; SBAR;
        MFMA16(0);
        SCHED0; SBAR;
        DSREAD_A(buf, 0, 1);
        SCHED0; SBAR;
        MFMA16(1);
        SCHED0;
        asm volatile("s_waitcnt vmcnt(0)" ::: "memory");
        SBAR;
        DSREAD_B(buf, 1); DSREAD_A(buf, 1, 0);
        SCHED0; SBAR;
        MFMA16(0);
        SCHED0; SBAR;
        DSREAD_A(buf, 1, 1);
        SCHED0; SBAR;
        MFMA16(1);
    }
#undef DSREAD_B
#undef DSREAD_A
#undef MFMA16

    const int rr = sk * 4;
    const int cc = fr;
    #pragma unroll
    for (int mf = 0; mf < 8; mf++) {
        #pragma unroll
        for (int nf = 0; nf < 4; nf++) {
            int col = bn + wc * 64 + nf * 16 + cc;
            #pragma unroll
            for (int q = 0; q < 4; q++) {
                int row = bm + wr * 128 + mf * 16 + rr + q;
                float v = acc[mf][nf][q];
                if constexpr (EPI == 0)
                    ((float*)outp)[(size_t)row * ldc + col] = v;
                else
                    ((unsigned short*)outp)[(size_t)row * ldc + col] = f2b(v);
            }
        }
    }
}

// ---------------- host ----------------
extern "C" void kernel_launch(void* const* d_in, const int* in_sizes, int n_in,
                              void* d_out, int out_size, void* d_ws, size_t ws_size,
                              hipStream_t stream) {
    const float* hs        = (const float*)d_in[0];
    const float* resi      = (const float*)d_in[1];
    const float* norm_w    = (const float*)d_in[2];
    const float* in_proj_w = (const float*)d_in[3];
    const float* conv_w    = (const float*)d_in[4];
    const float* conv_b    = (const float*)d_in[5];
    const float* x_proj_w  = (const float*)d_in[6];
    const float* dt_proj_w = (const float*)d_in[7];
    const float* dt_proj_b = (const float*)d_in[8];
    const float* A_log     = (const float*)d_in[9];
    const float* Dp        = (const float*)d_in[10];
    const float* out_proj_w= (const float*)d_in[11];
    const float* norm2_w   = (const float*)d_in[12];
    const float* fc1_w     = (const float*)d_in[13];
    const float* fc2_w     = (const float*)d_in[14];

    static bool attrDone = false;
    if (!attrDone) {
        hipFuncSetAttribute(reinterpret_cast<const void*>(k_gemm256<0>),
                            hipFuncAttributeMaxDynamicSharedMemorySize, 131072);
        hipFuncSetAttribute(reinterpret_cast<const void*>(k_gemm256<1>),
                            hipFuncAttributeMaxDynamicSharedMemorySize, 131072);
        attrDone = true;
    }

    char* ws = (char*)d_ws;
    size_t off = 0;
    auto alloc = [&](size_t bytes) {
        void* p = ws + off;
        off = (off + bytes + 255) & ~(size_t)255;
        return p;
    };

    // --- workspace overlay (total ~116 MB) ---
    unsigned short* xzB  = (unsigned short*)alloc((size_t)BL_ * 2 * DIN_ * 2);
    unsigned short* fcB  = xzB;                              // 32MB, [k9..k10]
    unsigned short* gB   = xzB + (size_t)BL_ * 2 * H_;       // 16MB, [k10..k11]
    unsigned short* mixB = gB  + (size_t)BL_ * H_;           // 16MB, [k8..k9]
    void* S_xc = alloc((size_t)BL_ * DIN_ * 2);
    unsigned short* hnB    = (unsigned short*)S_xc;
    unsigned short* xconvB = (unsigned short*)S_xc;
    float*          mixF   = (float*)S_xc;
    unsigned short* dblB = (unsigned short*)alloc((size_t)BL_ * 96 * 2);
    unsigned short* inprojB  = (unsigned short*)alloc((size_t)2 * DIN_ * DM_ * 2);  // 8MB, dead after k2
    unsigned short* xprojB   = (unsigned short*)alloc((size_t)128 * DIN_ * 2);      // 0.5MB, dead after k4
    unsigned short* dtprojB  = (unsigned short*)alloc((size_t)DIN_ * R_ * 2);       // dead after k5
    unsigned short* outprojB = (unsigned short*)alloc((size_t)DM_ * DIN_ * 2);
    unsigned short* fc1B     = (unsigned short*)alloc((size_t)2 * H_ * DM_ * 2);
    unsigned short* fc2B     = (unsigned short*)alloc((size_t)DM_ * H_ * 2);

    // scan scratch (bf16): Q = 8MB fits inprojB exactly; sumdt = 0.5MB fits xprojB exactly
    unsigned short* scanQ  = inprojB;   // [B][CCH][DIN][16] bf16
    unsigned short* scanSd = xprojB;    // [B][CCH][DIN]     bf16

    float* outMain = (float*)d_out;
    float* outRes2 = (float*)d_out + (size_t)BL_ * DM_;
    float*          resF = outMain;
    unsigned short* dtyB = (unsigned short*)outRes2;

    {
        int n;
        n = 2 * DIN_ * DM_; k_cvt<<<(n + 255) / 256, 256, 0, stream>>>(in_proj_w, inprojB, n);
        n = 96 * DIN_;      k_cvt<<<(n + 255) / 256, 256, 0, stream>>>(x_proj_w, xprojB, n);
        n = 32 * DIN_;      k_fill0<<<(n + 255) / 256, 256, 0, stream>>>(xprojB + 96 * DIN_, n);
        n = DIN_ * R_;      k_cvt<<<(n + 255) / 256, 256, 0, stream>>>(dt_proj_w, dtprojB, n);
        n = DM_ * DIN_;     k_cvt<<<(n + 255) / 256, 256, 0, stream>>>(out_proj_w, outprojB, n);
        n = 2 * H_ * DM_;   k_cvt<<<(n + 255) / 256, 256, 0, stream>>>(fc1_w, fc1B, n);
        n = DM_ * H_;       k_cvt<<<(n + 255) / 256, 256, 0, stream>>>(fc2_w, fc2B, n);
    }

    // 1) res = hs + residual ; hn = rmsnorm(res)
    k_add_rmsnorm<<<BL_, 256, 0, stream>>>(hs, resi, norm_w, resF, hnB);

    // 2) xz = hn @ in_proj^T   (M=8192, N=4096, K=1024)
    k_gemm256<1><<<dim3(2 * DIN_ / 256, BL_ / 256), 512, 131072, stream>>>(
        hnB, DM_, inprojB, DM_, (void*)xzB, 2 * DIN_, DM_);

    // 3) depthwise conv + silu
    k_conv_silu<<<(BL_ * DIN_ + 255) / 256, 256, 0, stream>>>(xzB, conv_w, conv_b, xconvB);

    // 4) dbl = x @ x_proj^T    (M=8192, N=128(pad), K=2048, store 96)
    k_gemm<1><<<dim3(1, BL_ / 128), 256, 0, stream>>>(
        xconvB, DIN_, xprojB, DIN_, (void*)dblB, 96, nullptr, BL_, 128, DIN_, 96);

    // 5) dt = softplus(dt_low @ dt_proj^T + b) -> bf16  (M=8192, N=2048, K=64)
    k_gemm<2><<<dim3(DIN_ / 128, BL_ / 128), 256, 0, stream>>>(
        dblB, 96, dtprojB, R_, (void*)dtyB, DIN_, dt_proj_b, BL_, DIN_, R_, DIN_);

    // 6) chunked selective scan (pass1 -> combine -> pass3)
    k_scan_p1<<<dim3(B_ * (DIN_ / 256), CCH), 256, 0, stream>>>(
        dtyB, xconvB, dblB, A_log, scanQ, scanSd);
    k_scan_comb<<<(B_ * DIN_ * NS_) / 256, 256, 0, stream>>>(scanQ, scanSd, A_log);
    k_scan_p3<<<dim3(B_ * (DIN_ / 256), CCH), 256, 0, stream>>>(
        dtyB, xconvB, dblB, A_log, Dp, xzB, scanQ);

    // 7) mix = y @ out_proj^T  (M=8192, N=1024, K=2048)
    k_gemm256<0><<<dim3(DM_ / 256, BL_ / 256), 512, 131072, stream>>>(
        dtyB, DIN_, outprojB, DIN_, (void*)mixF, DM_, DIN_);

    // 8) res2 = rmsnorm(mix + res) -> d_out[1]; mixB = bf16(mix)
    k_add_rmsnorm2<<<BL_, 256, 0, stream>>>(mixF, resF, norm2_w, outRes2, mixB);

    // 9) fc = mix @ fc1^T      (M=8192, N=2048, K=1024)
    k_gemm256<1><<<dim3(2 * H_ / 256, BL_ / 256), 512, 131072, stream>>>(
        mixB, DM_, fc1B, DM_, (void*)fcB, 2 * H_, DM_);

    // 10) g = y * silu(gate)
    k_gate<<<(BL_ * H_ + 255) / 256, 256, 0, stream>>>(fcB, gB);

    // 11) out = g @ fc2^T      (M=8192, N=1024, K=1024) -> d_out[0]
    k_gemm256<0><<<dim3(DM_ / 256, BL_ / 256), 512, 131072, stream>>>(
        gB, H_, fc2B, H_, (void*)outMain, DM_, H_);
}

// Round 6
// 550.819 us; speedup vs baseline: 3.6148x; 1.1174x over previous
//
#include <hip/hip_runtime.h>
#include <hip/hip_bf16.h>

#define B_   4
#define L_   2048
#define DM_  1024
#define DIN_ 2048
#define NS_  16
#define R_   64
#define KC_  4
#define H_   1024
#define BL_  (B_ * L_)   // 8192 tokens
#define CCH  32          // scan chunks
#define CHL  (L_ / CCH)  // 64 steps per chunk

typedef __attribute__((ext_vector_type(4))) float f32x4;
typedef __attribute__((ext_vector_type(8))) short bf16x8;
typedef __attribute__((ext_vector_type(8))) unsigned short u16x8;

__device__ __forceinline__ float b2f(unsigned short u) {
    union { unsigned int i; float f; } v; v.i = ((unsigned int)u) << 16; return v.f;
}
__device__ __forceinline__ unsigned short f2b(float f) {
    union { float f; unsigned int i; } v; v.f = f;
    unsigned int r = v.i + 0x7fffu + ((v.i >> 16) & 1u);
    return (unsigned short)(r >> 16);
}
__device__ __forceinline__ float sigmoidf_(float x) { return 1.f / (1.f + __expf(-x)); }
__device__ __forceinline__ float softplusf_(float x) { return (x > 20.f) ? x : log1pf(__expf(x)); }

__device__ __forceinline__ void gload16(const unsigned short* g, unsigned short* l) {
    __builtin_amdgcn_global_load_lds(
        (__attribute__((address_space(1))) void*)(g),
        (__attribute__((address_space(3))) void*)(l), 16, 0, 0);
}

// ---------------- small elementwise kernels ----------------
__global__ void k_cvt(const float* __restrict__ in, unsigned short* __restrict__ out, int n) {
    int i = blockIdx.x * blockDim.x + threadIdx.x;
    if (i < n) out[i] = f2b(in[i]);
}
__global__ void k_fill0(unsigned short* __restrict__ out, int n) {
    int i = blockIdx.x * blockDim.x + threadIdx.x;
    if (i < n) out[i] = 0;
}
// fp32 copy of B/C columns of dbl: dblF[row][0..31] = dbl[row][64..95]
__global__ void k_cvtBC(const unsigned short* __restrict__ dbl, float* __restrict__ dblF) {
    int i = blockIdx.x * 256 + threadIdx.x;
    if (i >= BL_ * 32) return;
    int row = i >> 5, n = i & 31;
    dblF[i] = b2f(dbl[(size_t)row * 96 + 64 + n]);
}

// res = a + b (fp32 out), hn = bf16(rmsnorm(res) * w)
__global__ __launch_bounds__(256)
void k_add_rmsnorm(const float* __restrict__ a, const float* __restrict__ b,
                   const float* __restrict__ w,
                   float* __restrict__ resOut, unsigned short* __restrict__ hnOut) {
    int row = blockIdx.x, tid = threadIdx.x;
    const float4* ap = (const float4*)(a + (size_t)row * DM_);
    const float4* bp = (const float4*)(b + (size_t)row * DM_);
    float4 va = ap[tid], vb = bp[tid];
    float4 s = make_float4(va.x + vb.x, va.y + vb.y, va.z + vb.z, va.w + vb.w);
    ((float4*)(resOut + (size_t)row * DM_))[tid] = s;
    float ss = s.x * s.x + s.y * s.y + s.z * s.z + s.w * s.w;
    #pragma unroll
    for (int m = 32; m >= 1; m >>= 1) ss += __shfl_xor(ss, m);
    __shared__ float red[4];
    if ((tid & 63) == 0) red[tid >> 6] = ss;
    __syncthreads();
    float tot = red[0] + red[1] + red[2] + red[3];
    float sc = rsqrtf(tot / (float)DM_ + 1e-5f);
    float4 vw = ((const float4*)w)[tid];
    unsigned short* hp = hnOut + (size_t)row * DM_ + tid * 4;
    *(ushort4*)hp = make_ushort4(f2b(s.x * sc * vw.x), f2b(s.y * sc * vw.y),
                                 f2b(s.z * sc * vw.z), f2b(s.w * sc * vw.w));
}

// res2 = rmsnorm(mix + res) * w (fp32 out), mixB = bf16(mix)
__global__ __launch_bounds__(256)
void k_add_rmsnorm2(const float* __restrict__ mix, const float* __restrict__ res,
                    const float* __restrict__ w,
                    float* __restrict__ res2Out, unsigned short* __restrict__ mixB) {
    int row = blockIdx.x, tid = threadIdx.x;
    const float4* mp = (const float4*)(mix + (size_t)row * DM_);
    const float4* rp = (const float4*)(res + (size_t)row * DM_);
    float4 vm = mp[tid], vr = rp[tid];
    float4 s = make_float4(vm.x + vr.x, vm.y + vr.y, vm.z + vr.z, vm.w + vr.w);
    unsigned short* mb = mixB + (size_t)row * DM_ + tid * 4;
    *(ushort4*)mb = make_ushort4(f2b(vm.x), f2b(vm.y), f2b(vm.z), f2b(vm.w));
    float ss = s.x * s.x + s.y * s.y + s.z * s.z + s.w * s.w;
    #pragma unroll
    for (int m = 32; m >= 1; m >>= 1) ss += __shfl_xor(ss, m);
    __shared__ float red[4];
    if ((tid & 63) == 0) red[tid >> 6] = ss;
    __syncthreads();
    float tot = red[0] + red[1] + red[2] + red[3];
    float sc = rsqrtf(tot / (float)DM_ + 1e-5f);
    float4 vw = ((const float4*)w)[tid];
    float4 o = make_float4(s.x * sc * vw.x, s.y * sc * vw.y, s.z * sc * vw.z, s.w * sc * vw.w);
    ((float4*)(res2Out + (size_t)row * DM_))[tid] = o;
}

// depthwise causal conv K=4 + bias + silu, register tap pipeline.
// block = (b, chunk of 8 t); 256 threads x 8 d = DIN.
__global__ __launch_bounds__(256)
void k_conv_silu(const unsigned short* __restrict__ xz,
                 const float* __restrict__ cw, const float* __restrict__ cb,
                 unsigned short* __restrict__ xc) {
    const int tid = threadIdx.x;
    const int d0 = tid * 8;
    const int b  = blockIdx.x >> 8;          // grid.x = B_ * 256
    const int t0 = (blockIdx.x & 255) * 8;
    const unsigned short* xbase = xz + (size_t)b * L_ * (2 * DIN_) + d0;
    unsigned short* obase = xc + (size_t)b * L_ * DIN_ + d0;

    float4 w[8];
    float bias[8];
    #pragma unroll
    for (int j = 0; j < 8; j++) {
        w[j] = ((const float4*)cw)[d0 + j];
        bias[j] = cb[d0 + j];
    }
    u16x8 zero = (u16x8){0, 0, 0, 0, 0, 0, 0, 0};
    u16x8 r0 = zero, r1 = zero, r2 = zero, r3;
    if (t0 >= 3) {
        r0 = *(const u16x8*)(xbase + (size_t)(t0 - 3) * (2 * DIN_));
        r1 = *(const u16x8*)(xbase + (size_t)(t0 - 2) * (2 * DIN_));
        r2 = *(const u16x8*)(xbase + (size_t)(t0 - 1) * (2 * DIN_));
    }
    #pragma unroll
    for (int tt = 0; tt < 8; tt++) {
        int t = t0 + tt;
        r3 = *(const u16x8*)(xbase + (size_t)t * (2 * DIN_));
        u16x8 out;
        #pragma unroll
        for (int j = 0; j < 8; j++) {
            float acc = bias[j] + w[j].x * b2f(r0[j]) + w[j].y * b2f(r1[j])
                                + w[j].z * b2f(r2[j]) + w[j].w * b2f(r3[j]);
            out[j] = f2b(acc * sigmoidf_(acc));
        }
        *(u16x8*)(obase + (size_t)t * DIN_) = out;
        r0 = r1; r1 = r2; r2 = r3;
    }
}

// g = y * silu(gate) from fc = [y | gate]
__global__ void k_gate(const unsigned short* __restrict__ fc, unsigned short* __restrict__ g) {
    int i = blockIdx.x * blockDim.x + threadIdx.x;
    if (i >= BL_ * H_) return;
    int h = i % H_;
    int row = i / H_;
    float y = b2f(fc[(size_t)row * (2 * H_) + h]);
    float gt = b2f(fc[(size_t)row * (2 * H_) + H_ + h]);
    g[i] = f2b(y * gt * sigmoidf_(gt));
}

// ---------------- chunked selective scan ----------------
// Thread-per-channel; B/C read from fp32 dblF with block-uniform addresses
// (scalarizable). No LDS, no barriers.
__global__ __launch_bounds__(256)
void k_scan_p1(const unsigned short* __restrict__ dty, const unsigned short* __restrict__ xc,
               const float* __restrict__ dblF, const float* __restrict__ A_log,
               unsigned short* __restrict__ Q, unsigned short* __restrict__ sumdt) {
    const int tid = threadIdx.x;
    const int d = (blockIdx.x & 7) * 256 + tid;
    const int b = blockIdx.x >> 3;
    const int c = blockIdx.y;
    const int t0 = c * CHL;

    float a[NS_], h[NS_];
    #pragma unroll
    for (int n = 0; n < NS_; n++) { a[n] = -__expf(A_log[d * NS_ + n]); h[n] = 0.f; }
    float sd = 0.f;

    const unsigned short* dp  = dty + (size_t)b * L_ * DIN_ + d;
    const unsigned short* xp  = xc  + (size_t)b * L_ * DIN_ + d;
    const float* bcp = dblF + (size_t)(b * L_ + t0) * 32;

    #pragma unroll 2
    for (int t = 0; t < CHL; t++) {
        int tg = t0 + t;
        float dtv = b2f(dp[(size_t)tg * DIN_]);
        float xv  = b2f(xp[(size_t)tg * DIN_]);
        sd += dtv;
        float bx = dtv * xv;
        const float* bc = bcp + t * 32;
        #pragma unroll
        for (int n = 0; n < NS_; n++)
            h[n] = __expf(dtv * a[n]) * h[n] + bx * bc[n];
    }
    unsigned short* q = Q + ((size_t)(b * CCH + c) * DIN_ + d) * NS_;
    u16x8 qa, qb;
    #pragma unroll
    for (int j = 0; j < 8; j++) { qa[j] = f2b(h[j]); qb[j] = f2b(h[8 + j]); }
    *(u16x8*)q = qa;
    *(u16x8*)(q + 8) = qb;
    sumdt[(size_t)(b * CCH + c) * DIN_ + d] = f2b(sd);
}

__global__ __launch_bounds__(256)
void k_scan_comb(unsigned short* __restrict__ Q, const unsigned short* __restrict__ sumdt,
                 const float* __restrict__ A_log) {
    int i = blockIdx.x * 256 + threadIdx.x;   // (b,d,n), 131072 total
    int n = i & 15;
    int d = (i >> 4) & (DIN_ - 1);
    int b = i >> 15;
    float a = -__expf(A_log[d * NS_ + n]);
    float h = 0.f;
    for (int c = 0; c < CCH; c++) {
        size_t base = ((size_t)(b * CCH + c) * DIN_ + d);
        float q  = b2f(Q[base * NS_ + n]);
        float sd = b2f(sumdt[base]);
        if (c > 0) Q[((size_t)(b * CCH + c - 1) * DIN_ + d) * NS_ + n] = f2b(h);
        h = __expf(a * sd) * h + q;
    }
}

__global__ __launch_bounds__(256)
void k_scan_p3(unsigned short* __restrict__ dty, const unsigned short* __restrict__ xc,
               const float* __restrict__ dblF, const float* __restrict__ A_log,
               const float* __restrict__ Dp, const unsigned short* __restrict__ xz,
               const unsigned short* __restrict__ Qh) {
    const int tid = threadIdx.x;
    const int d = (blockIdx.x & 7) * 256 + tid;
    const int b = blockIdx.x >> 3;
    const int c = blockIdx.y;
    const int t0 = c * CHL;

    float a[NS_], h[NS_];
    #pragma unroll
    for (int n = 0; n < NS_; n++) a[n] = -__expf(A_log[d * NS_ + n]);
    if (c == 0) {
        #pragma unroll
        for (int n = 0; n < NS_; n++) h[n] = 0.f;
    } else {
        const unsigned short* qh = Qh + ((size_t)(b * CCH + c - 1) * DIN_ + d) * NS_;
        u16x8 v0 = *(const u16x8*)qh;
        u16x8 v1 = *(const u16x8*)(qh + 8);
        #pragma unroll
        for (int j = 0; j < 8; j++) { h[j] = b2f(v0[j]); h[8 + j] = b2f(v1[j]); }
    }
    float Dd = Dp[d];

    unsigned short* dp = dty + (size_t)b * L_ * DIN_ + d;
    const unsigned short* xp  = xc + (size_t)b * L_ * DIN_ + d;
    const unsigned short* zp  = xz + (size_t)b * L_ * (2 * DIN_) + DIN_ + d;
    const float* bcp = dblF + (size_t)(b * L_ + t0) * 32;

    #pragma unroll 2
    for (int t = 0; t < CHL; t++) {
        int tg = t0 + t;
        float dtv = b2f(dp[(size_t)tg * DIN_]);
        float xv  = b2f(xp[(size_t)tg * DIN_]);
        float bx = dtv * xv;
        const float* bc = bcp + t * 32;
        float y = 0.f;
        #pragma unroll
        for (int n = 0; n < NS_; n++) {
            h[n] = __expf(dtv * a[n]) * h[n] + bx * bc[n];
            y += h[n] * bc[16 + n];
        }
        y += xv * Dd;
        float zv = b2f(zp[(size_t)tg * (2 * DIN_)]);
        dp[(size_t)tg * DIN_] = f2b(y * zv * sigmoidf_(zv));
    }
}

// ---------------- GEMM 128x128 (m97 structure) for small shapes ----------------
// EPI: 0 = fp32 store, 1 = bf16 store, 2 = bias + softplus + bf16 store
template <int EPI>
__global__ __launch_bounds__(256)
void k_gemm(const unsigned short* __restrict__ A, int lda,
            const unsigned short* __restrict__ Bw, int ldb,
            void* __restrict__ outp, int ldc, const float* __restrict__ bias,
            int M, int N, int Kd, int Nstore) {
    __shared__ unsigned short As[128 * 32];
    __shared__ unsigned short Bs[128 * 32];
    const int tid = threadIdx.x;
    const int lane = tid & 63;
    const int w = tid >> 6;
    const int wr = w >> 1, wc = w & 1;
    const int bm = blockIdx.y * 128, bn = blockIdx.x * 128;

    const int e0 = tid * 8;
    const int r0 = e0 >> 5;
    const int c0 = e0 & 31;
    const int r1 = r0 + 64;

    f32x4 acc[4][4];
    #pragma unroll
    for (int i = 0; i < 4; i++)
        #pragma unroll
        for (int j = 0; j < 4; j++) acc[i][j] = (f32x4){0.f, 0.f, 0.f, 0.f};

    const int fr = lane & 15, ko = (lane >> 4) * 8;

    for (int k0 = 0; k0 < Kd; k0 += 32) {
        gload16(A  + (size_t)(bm + r0) * lda + k0 + c0, &As[e0]);
        gload16(A  + (size_t)(bm + r1) * lda + k0 + c0, &As[e0 + 2048]);
        gload16(Bw + (size_t)(bn + r0) * ldb + k0 + c0, &Bs[e0]);
        gload16(Bw + (size_t)(bn + r1) * ldb + k0 + c0, &Bs[e0 + 2048]);
        __syncthreads();
        bf16x8 af[4], bv[4];
        #pragma unroll
        for (int i = 0; i < 4; i++)
            af[i] = *(const bf16x8*)&As[(wr * 64 + i * 16 + fr) * 32 + ko];
        #pragma unroll
        for (int j = 0; j < 4; j++)
            bv[j] = *(const bf16x8*)&Bs[(wc * 64 + j * 16 + fr) * 32 + ko];
        #pragma unroll
        for (int i = 0; i < 4; i++)
            #pragma unroll
            for (int j = 0; j < 4; j++)
                acc[i][j] = __builtin_amdgcn_mfma_f32_16x16x32_bf16(af[i], bv[j], acc[i][j], 0, 0, 0);
        __syncthreads();
    }

    const int rr = (lane >> 4) * 4;
    const int cc = lane & 15;
    #pragma unroll
    for (int i = 0; i < 4; i++) {
        #pragma unroll
        for (int j = 0; j < 4; j++) {
            int col = bn + wc * 64 + j * 16 + cc;
            if (col >= Nstore) continue;
            #pragma unroll
            for (int q = 0; q < 4; q++) {
                int row = bm + wr * 64 + i * 16 + rr + q;
                float v = acc[i][j][q];
                if constexpr (EPI == 2) { v += bias[col]; v = softplusf_(v); }
                if constexpr (EPI == 0)
                    ((float*)outp)[(size_t)row * ldc + col] = v;
                else
                    ((unsigned short*)outp)[(size_t)row * ldc + col] = f2b(v);
            }
        }
    }
}

// ---------------- GEMM 256x256, 8-wave, k-sliced LDS, counted-vmcnt pipeline ----
// Swizzle slot: rows of 64B, slot = ((r ^ (r>>2)) & 3) * 16B -> same-parity rows
// spread over 4 16B slots, worst 2-way bank aliasing (free).
#define SBAR   __builtin_amdgcn_s_barrier()
#define SCHED0 __builtin_amdgcn_sched_barrier(0)
#define SLOT(r) ((((r) ^ ((r) >> 2)) & 3) << 4)

template <int EPI>
__global__ __launch_bounds__(512, 2)
void k_gemm256(const unsigned short* __restrict__ Aptr, int lda,
               const unsigned short* __restrict__ Bptr, int ldb,
               void* __restrict__ outp, int ldc, int Kd) {
    extern __shared__ unsigned short lds[];
    const int tid  = threadIdx.x;
    const int lane = tid & 63;
    const int wid  = tid >> 6;
    const int wr = wid >> 2, wc = wid & 3;
    const int bm = blockIdx.y * 256, bn = blockIdx.x * 256;
    const int fr = lane & 15, sk = lane >> 4;

    f32x4 acc[8][4];
    #pragma unroll
    for (int i = 0; i < 8; i++)
        #pragma unroll
        for (int j = 0; j < 4; j++) acc[i][j] = (f32x4){0.f, 0.f, 0.f, 0.f};

    const int NT = Kd >> 6;

    const int o0 = tid * 16, o1 = (512 + tid) * 16;
    const int sr0 = o0 >> 6, sr1 = o1 >> 6;
    const int sc0 = (o0 & 63) ^ SLOT(sr0);
    const int sc1 = (o1 & 63) ^ SLOT(sr1);
    const unsigned short* Ag0 = Aptr + (size_t)(bm + sr0) * lda + (sc0 >> 1);
    const unsigned short* Ag1 = Aptr + (size_t)(bm + sr1) * lda + (sc1 >> 1);
    const unsigned short* Bg0 = Bptr + (size_t)(bn + sr0) * ldb + (sc0 >> 1);
    const unsigned short* Bg1 = Bptr + (size_t)(bn + sr1) * ldb + (sc1 >> 1);
    unsigned short* L0 = lds + (o0 >> 1);
    unsigned short* L1 = lds + (o1 >> 1);

    auto stageA = [&](int buf, int ks, int kt) {
        int s = (buf * 2 + ks) * 8192;
        gload16(Ag0 + kt * 64 + ks * 32, L0 + s);
        gload16(Ag1 + kt * 64 + ks * 32, L1 + s);
    };
    auto stageB = [&](int buf, int ks, int kt) {
        int s = 32768 + (buf * 2 + ks) * 8192;
        gload16(Bg0 + kt * 64 + ks * 32, L0 + s);
        gload16(Bg1 + kt * 64 + ks * 32, L1 + s);
    };

    const int rsw  = (sk * 16) ^ SLOT(fr);
    const int aoff = (wr * 128 + fr) * 32 + (rsw >> 1);
    const int boff = (wc * 64  + fr) * 32 + (rsw >> 1);

#define DSREAD_B(buf, ks) { _Pragma("unroll") for (int n = 0; n < 4; n++) \
    bv[n] = *(const bf16x8*)&lds[32768 + ((buf)*2+(ks))*8192 + boff + n*512]; }
#define DSREAD_A(buf, ks, mh) { _Pragma("unroll") for (int m = 0; m < 4; m++) \
    af[m] = *(const bf16x8*)&lds[((buf)*2+(ks))*8192 + aoff + ((mh)*4+m)*512]; }
#define MFMA16(mh) { __builtin_amdgcn_s_setprio(1); \
    _Pragma("unroll") for (int m = 0; m < 4; m++) \
      _Pragma("unroll") for (int n = 0; n < 4; n++) \
        acc[(mh)*4+m][n] = __builtin_amdgcn_mfma_f32_16x16x32_bf16(af[m], bv[n], acc[(mh)*4+m][n], 0, 0, 0); \
    __builtin_amdgcn_s_setprio(0); }

    stageA(0, 0, 0); stageB(0, 0, 0); stageA(0, 1, 0); stageB(0, 1, 0);
    SCHED0;
    asm volatile("s_waitcnt vmcnt(4)" ::: "memory");
    SBAR;

    int buf = 0;
    for (int kt = 0; kt < NT - 1; ++kt) {
        bf16x8 af[4], bv[4];
        DSREAD_B(buf, 0); DSREAD_A(buf, 0, 0);
        stageA(buf ^ 1, 0, kt + 1);
        SCHED0; SBAR;
        MFMA16(0);
        SCHED0; SBAR;
        DSREAD_A(buf, 0, 1);
        stageB(buf ^ 1, 0, kt + 1);
        SCHED0; SBAR;
        MFMA16(1);
        SCHED0;
        asm volatile("s_waitcnt vmcnt(4)" ::: "memory");
        SBAR;
        DSREAD_B(buf, 1); DSREAD_A(buf, 1, 0);
        stageA(buf ^ 1, 1, kt + 1);
        SCHED0; SBAR;
        MFMA16(0);
        SCHED0; SBAR;
        DSREAD_A(buf, 1, 1);
        stageB(buf ^ 1, 1, kt + 1);
        SCHED0; SBAR;
        MFMA16(1);
        SCHED0;
        asm volatile("s_waitcnt vmcnt(4)" ::: "memory");
        SBAR;
        buf ^= 1;
    }
    {
        bf16x8 af[4], bv[4];
        DSREAD_B(buf, 0); DSREAD_A(buf, 0, 0);
        SCHED0; SBAR;
        MFMA16(0);
        SCHED0; SBAR;
        DSREAD_A(buf, 0, 1);
        SCHED0; SBAR;
        MFMA16(1);
        SCHED0;
        asm volatile("s_waitcnt vmcnt(0)" ::: "memory");
        SBAR;
        DSREAD_B(buf, 1); DSREAD_A(buf, 1, 0);
        SCHED0; SBAR;
        MFMA16(0);
        SCHED0; SBAR;
        DSREAD_A(buf, 1, 1);
        SCHED0; SBAR;
        MFMA16(1);
    }
#undef DSREAD_B
#undef DSREAD_A
#undef MFMA16

    const int rr = sk * 4;
    const int cc = fr;
    #pragma unroll
    for (int mf = 0; mf < 8; mf++) {
        #pragma unroll
        for (int nf = 0; nf < 4; nf++) {
            int col = bn + wc * 64 + nf * 16 + cc;
            #pragma unroll
            for (int q = 0; q < 4; q++) {
                int row = bm + wr * 128 + mf * 16 + rr + q;
                float v = acc[mf][nf][q];
                if constexpr (EPI == 0)
                    ((float*)outp)[(size_t)row * ldc + col] = v;
                else
                    ((unsigned short*)outp)[(size_t)row * ldc + col] = f2b(v);
            }
        }
    }
}

// ---------------- host ----------------
extern "C" void kernel_launch(void* const* d_in, const int* in_sizes, int n_in,
                              void* d_out, int out_size, void* d_ws, size_t ws_size,
                              hipStream_t stream) {
    const float* hs        = (const float*)d_in[0];
    const float* resi      = (const float*)d_in[1];
    const float* norm_w    = (const float*)d_in[2];
    const float* in_proj_w = (const float*)d_in[3];
    const float* conv_w    = (const float*)d_in[4];
    const float* conv_b    = (const float*)d_in[5];
    const float* x_proj_w  = (const float*)d_in[6];
    const float* dt_proj_w = (const float*)d_in[7];
    const float* dt_proj_b = (const float*)d_in[8];
    const float* A_log     = (const float*)d_in[9];
    const float* Dp        = (const float*)d_in[10];
    const float* out_proj_w= (const float*)d_in[11];
    const float* norm2_w   = (const float*)d_in[12];
    const float* fc1_w     = (const float*)d_in[13];
    const float* fc2_w     = (const float*)d_in[14];

    static bool attrDone = false;
    if (!attrDone) {
        hipFuncSetAttribute(reinterpret_cast<const void*>(k_gemm256<0>),
                            hipFuncAttributeMaxDynamicSharedMemorySize, 131072);
        hipFuncSetAttribute(reinterpret_cast<const void*>(k_gemm256<1>),
                            hipFuncAttributeMaxDynamicSharedMemorySize, 131072);
        attrDone = true;
    }

    char* ws = (char*)d_ws;
    size_t off = 0;
    auto alloc = [&](size_t bytes) {
        void* p = ws + off;
        off = (off + bytes + 255) & ~(size_t)255;
        return p;
    };

    // --- workspace overlay (total ~117 MB) ---
    unsigned short* xzB  = (unsigned short*)alloc((size_t)BL_ * 2 * DIN_ * 2);
    unsigned short* fcB  = xzB;                              // 32MB, [k9..k10]
    unsigned short* gB   = xzB + (size_t)BL_ * 2 * H_;       // 16MB, [k10..k11]
    unsigned short* mixB = gB  + (size_t)BL_ * H_;           // 16MB, [k8..k9]
    void* S_xc = alloc((size_t)BL_ * DIN_ * 2);
    unsigned short* hnB    = (unsigned short*)S_xc;
    unsigned short* xconvB = (unsigned short*)S_xc;
    float*          mixF   = (float*)S_xc;
    unsigned short* dblB = (unsigned short*)alloc((size_t)BL_ * 96 * 2);
    unsigned short* inprojB  = (unsigned short*)alloc((size_t)2 * DIN_ * DM_ * 2);  // 8MB, dead after k2
    unsigned short* xprojB   = (unsigned short*)alloc((size_t)128 * DIN_ * 2);      // 0.5MB, dead after k4
    unsigned short* dtprojB  = (unsigned short*)alloc((size_t)DIN_ * R_ * 2);       // dead after k5
    unsigned short* outprojB = (unsigned short*)alloc((size_t)DM_ * DIN_ * 2);
    unsigned short* fc1B     = (unsigned short*)alloc((size_t)2 * H_ * DM_ * 2);
    unsigned short* fc2B     = (unsigned short*)alloc((size_t)DM_ * H_ * 2);
    float*          dblF     = (float*)alloc((size_t)BL_ * 32 * 4);                 // 1MB fp32 B/C

    // scan scratch (bf16): Q = 8MB fits inprojB exactly; sumdt = 0.5MB fits xprojB
    unsigned short* scanQ  = inprojB;   // [B][CCH][DIN][16] bf16
    unsigned short* scanSd = xprojB;    // [B][CCH][DIN]     bf16

    float* outMain = (float*)d_out;
    float* outRes2 = (float*)d_out + (size_t)BL_ * DM_;
    float*          resF = outMain;
    unsigned short* dtyB = (unsigned short*)outRes2;

    {
        int n;
        n = 2 * DIN_ * DM_; k_cvt<<<(n + 255) / 256, 256, 0, stream>>>(in_proj_w, inprojB, n);
        n = 96 * DIN_;      k_cvt<<<(n + 255) / 256, 256, 0, stream>>>(x_proj_w, xprojB, n);
        n = 32 * DIN_;      k_fill0<<<(n + 255) / 256, 256, 0, stream>>>(xprojB + 96 * DIN_, n);
        n = DIN_ * R_;      k_cvt<<<(n + 255) / 256, 256, 0, stream>>>(dt_proj_w, dtprojB, n);
        n = DM_ * DIN_;     k_cvt<<<(n + 255) / 256, 256, 0, stream>>>(out_proj_w, outprojB, n);
        n = 2 * H_ * DM_;   k_cvt<<<(n + 255) / 256, 256, 0, stream>>>(fc1_w, fc1B, n);
        n = DM_ * H_;       k_cvt<<<(n + 255) / 256, 256, 0, stream>>>(fc2_w, fc2B, n);
    }

    // 1) res = hs + residual ; hn = rmsnorm(res)
    k_add_rmsnorm<<<BL_, 256, 0, stream>>>(hs, resi, norm_w, resF, hnB);

    // 2) xz = hn @ in_proj^T   (M=8192, N=4096, K=1024)
    k_gemm256<1><<<dim3(2 * DIN_ / 256, BL_ / 256), 512, 131072, stream>>>(
        hnB, DM_, inprojB, DM_, (void*)xzB, 2 * DIN_, DM_);

    // 3) depthwise conv + silu (register tap pipeline)
    k_conv_silu<<<B_ * 256, 256, 0, stream>>>(xzB, conv_w, conv_b, xconvB);

    // 4) dbl = x @ x_proj^T    (M=8192, N=128(pad), K=2048, store 96)
    k_gemm<1><<<dim3(1, BL_ / 128), 256, 0, stream>>>(
        xconvB, DIN_, xprojB, DIN_, (void*)dblB, 96, nullptr, BL_, 128, DIN_, 96);

    // 4b) fp32 B/C columns for the scan
    k_cvtBC<<<(BL_ * 32) / 256, 256, 0, stream>>>(dblB, dblF);

    // 5) dt = softplus(dt_low @ dt_proj^T + b) -> bf16  (M=8192, N=2048, K=64)
    k_gemm<2><<<dim3(DIN_ / 128, BL_ / 128), 256, 0, stream>>>(
        dblB, 96, dtprojB, R_, (void*)dtyB, DIN_, dt_proj_b, BL_, DIN_, R_, DIN_);

    // 6) chunked selective scan (pass1 -> combine -> pass3)
    k_scan_p1<<<dim3(B_ * (DIN_ / 256), CCH), 256, 0, stream>>>(
        dtyB, xconvB, dblF, A_log, scanQ, scanSd);
    k_scan_comb<<<(B_ * DIN_ * NS_) / 256, 256, 0, stream>>>(scanQ, scanSd, A_log);
    k_scan_p3<<<dim3(B_ * (DIN_ / 256), CCH), 256, 0, stream>>>(
        dtyB, xconvB, dblF, A_log, Dp, xzB, scanQ);

    // 7) mix = y @ out_proj^T  (M=8192, N=1024, K=2048)
    k_gemm256<0><<<dim3(DM_ / 256, BL_ / 256), 512, 131072, stream>>>(
        dtyB, DIN_, outprojB, DIN_, (void*)mixF, DM_, DIN_);

    // 8) res2 = rmsnorm(mix + res) -> d_out[1]; mixB = bf16(mix)
    k_add_rmsnorm2<<<BL_, 256, 0, stream>>>(mixF, resF, norm2_w, outRes2, mixB);

    // 9) fc = mix @ fc1^T      (M=8192, N=2048, K=1024)
    k_gemm256<1><<<dim3(2 * H_ / 256, BL_ / 256), 512, 131072, stream>>>(
        mixB, DM_, fc1B, DM_, (void*)fcB, 2 * H_, DM_);

    // 10) g = y * silu(gate)
    k_gate<<<(BL_ * H_ + 255) / 256, 256, 0, stream>>>(fcB, gB);

    // 11) out = g @ fc2^T      (M=8192, N=1024, K=1024) -> d_out[0]
    k_gemm256<0><<<dim3(DM_ / 256, BL_ / 256), 512, 131072, stream>>>(
        gB, H_, fc2B, H_, (void*)outMain, DM_, H_);
}